// Round 5
// baseline (502.892 us; speedup 1.0000x reference)
//
#include <hip/hip_runtime.h>
#include <hip/hip_bf16.h>

// TLSTM forecaster. R5: per-wave L0/L1 software pipeline (L1 lagged 1 step),
// 2 barriers/step, all gate weights in registers (wf0 15 + wf1 24 frags),
// BWd0/1 in LDS (stride 136 = conflict-free), hist/decay/mask double-buffered.
// B=4096, L=64, D=16, H=128, NL=2, FUT*MD=60, HEAD_IN=144.
// grid=256 x 512 thr; block owns 16 batch rows; wave owns 16 N-cols.
// Gate order [i, o, c] (reference's f-gate is dead code).
//
// MFMA 16x16x32 bf16 layouts:
//   A[m=lane&15][k=(lane>>4)*8+j]   B[k][n=lane&15] (packed BT[n][k])
//   D[row=(lane>>4)*4+r][col=lane&15]

typedef __bf16 bf16x8 __attribute__((ext_vector_type(8)));
typedef float  f32x4  __attribute__((ext_vector_type(4)));

__device__ __forceinline__ f32x4 mfma16(bf16x8 a, bf16x8 b, f32x4 c) {
  return __builtin_amdgcn_mfma_f32_16x16x32_bf16(a, b, c, 0, 0, 0);
}
__device__ __forceinline__ float sigmf(float x) {
  return __fdividef(1.f, 1.f + __expf(-x));
}
__device__ __forceinline__ float tanhfast(float x) {
  return 1.f - __fdividef(2.f, 1.f + __expf(2.f * x));
}

// ---------------- ws layout (bytes) ----------------
// BT0  : [384][160] bf16 @ 0        (k 0..15 = Wp@Wx0 fold, 16..31 zeros, 32..159 Uh0)
// BWd0 : [128][128] bf16 @ 122880
// BT1  : [384][256] bf16 @ 155648   (k 0..127 = Wx1, 128..255 = Uh1)
// BWd1 : [128][128] bf16 @ 352256
// bz0  : [384] f32       @ 385024
#define OFF_BWD0 122880
#define OFF_BT1  155648
#define OFF_BWD1 352256
#define OFF_BZ0  385024

// ---------------- dynamic LDS layout (bytes) ----------------
#define S_BWD0  0        // [128][136] bf16 = 34816
#define S_BWD1  34816    // [128][136] bf16 = 34816
#define S_AH    69632    // [2][16][40] bf16 = 2560 (cols 16..31 zero)
#define S_A0H   72192    // [16][136] bf16 = 4352 (h0)
#define S_A1    76544    // [16][264] bf16 = 8448 ([h0_new | h1])
#define S_AT0   84992    // [16][136] bf16 = 4352
#define S_AT1   89344    // [16][136] bf16 = 4352
#define S_DM    93696    // [2][2][16] f32 = 256  ([slot][decay/mask][row])
#define S_LAST  93952    // [16] int
#define S_TOTAL 94016
// head-stage aliases (over BWd; all BWd reads done by then):
#define S_STATE 0        // [16][144] f32 = 9216
#define S_A1L   9216     // [16][128] f32 = 8192
#define S_REDS  17408    // [16][16] f32
#define S_REDQ  18432    // [16][16] f32

__global__ void tlstm_fold(const float* __restrict__ Wp, const float* __restrict__ bp,
                           const float* __restrict__ Wx, const float* __restrict__ bx,
                           __bf16* __restrict__ BT0, float* __restrict__ bz0) {
  int idx = blockIdx.x * 256 + threadIdx.x;
  if (idx >= 384 * 17) return;
  int n = idx / 17, kk = idx % 17;
  int npr = n & 127, gs = (n >> 7) + 1;                    // src gates 1,2,3 = i,o,c
  const float* wxcol = Wx + (gs * 128) * 128 + npr;        // Wx[0][gs][h][npr]
  if (kk < 16) {
    const float* wprow = Wp + kk * 128;
    float s = 0.f;
    for (int h = 0; h < 128; ++h) s += wprow[h] * wxcol[h * 128];
    BT0[n * 160 + kk] = (__bf16)s;
  } else {
    float s = bx[gs * 128 + npr];
    for (int h = 0; h < 128; ++h) s += bp[h] * wxcol[h * 128];
    bz0[n] = s;
    for (int k2 = 16; k2 < 32; ++k2) BT0[n * 160 + k2] = (__bf16)0.f;  // zero K-pad
  }
}

__global__ void tlstm_pack(const float* __restrict__ Wx, const float* __restrict__ Uh,
                           const float* __restrict__ Wd,
                           __bf16* __restrict__ BT0, __bf16* __restrict__ BWd0,
                           __bf16* __restrict__ BT1, __bf16* __restrict__ BWd1) {
  int e = blockIdx.x * 256 + threadIdx.x;
  if (e < 49152) {                                  // BT0 Uh0 region
    int n = e >> 7, k = e & 127, npr = n & 127, gs = (n >> 7) + 1;
    BT0[n * 160 + 32 + k] = (__bf16)Uh[(gs * 128 + k) * 128 + npr];
  } else if (e < 65536) {                           // BWd0 (dense [n][k])
    int e2 = e - 49152; int n = e2 >> 7, k = e2 & 127;
    BWd0[n * 128 + k] = (__bf16)Wd[k * 128 + n];
  } else if (e < 163840) {                          // BT1 = [Wx1 ; Uh1]
    int e2 = e - 65536; int n = e2 >> 8, k = e2 & 255;
    int npr = n & 127, gs = (n >> 7) + 1;
    float v = (k < 128) ? Wx[((4 + gs) * 128 + k) * 128 + npr]
                        : Uh[((4 + gs) * 128 + (k - 128)) * 128 + npr];
    BT1[n * 256 + k] = (__bf16)v;
  } else if (e < 180224) {                          // BWd1
    int e2 = e - 163840; int n = e2 >> 7, k = e2 & 127;
    BWd1[n * 128 + k] = (__bf16)Wd[(128 + k) * 128 + n];
  }
}

__global__ __launch_bounds__(512, 1) void tlstm_main(
    const float* __restrict__ hist, const float* __restrict__ hmask,
    const __bf16* __restrict__ BT0, const __bf16* __restrict__ BWd0,
    const __bf16* __restrict__ BT1, const __bf16* __restrict__ BWd1,
    const float* __restrict__ bz0, const float* __restrict__ bx,
    const float* __restrict__ bd, const float* __restrict__ Wt,
    const float* __restrict__ bt, const float* __restrict__ lng,
    const float* __restrict__ lnb, const float* __restrict__ W1,
    const float* __restrict__ b1, const float* __restrict__ W2,
    const float* __restrict__ b2, float* __restrict__ out) {
  extern __shared__ __align__(16) char smem[];
  __bf16* BWD0L = (__bf16*)(smem + S_BWD0);
  __bf16* BWD1L = (__bf16*)(smem + S_BWD1);
  __bf16 (*AH)[16][40]  = (__bf16(*)[16][40])(smem + S_AH);
  __bf16 (*A0H)[136]    = (__bf16(*)[136])(smem + S_A0H);
  __bf16 (*A1)[264]     = (__bf16(*)[264])(smem + S_A1);
  __bf16 (*AT0)[136]    = (__bf16(*)[136])(smem + S_AT0);
  __bf16 (*AT1)[136]    = (__bf16(*)[136])(smem + S_AT1);
  float (*dmL)[2][16]   = (float(*)[2][16])(smem + S_DM);
  int*   lastL          = (int*)(smem + S_LAST);
  float (*stateL)[144]  = (float(*)[144])(smem + S_STATE);
  float (*a1L)[128]     = (float(*)[128])(smem + S_A1L);
  float (*redS)[16]     = (float(*)[16])(smem + S_REDS);
  float (*redQ)[16]     = (float(*)[16])(smem + S_REDQ);

  const int tid  = threadIdx.x;
  const int wave = tid >> 6;
  const int lane = tid & 63;
  const int q    = lane >> 4;
  const int c16  = lane & 15;
  const int q8   = q * 8;
  const int b0   = blockIdx.x * 16;
  const int nc   = wave * 16 + c16;  // owned N-column (0..127)

  // ---- one-time init ----
  // BWd ws(dense 128) -> LDS (stride 136)
  for (int i = tid; i < 2048; i += 512) {
    int row = i >> 4, col8 = (i & 15) * 8;
    *(bf16x8*)(BWD0L + row * 136 + col8) = *(const bf16x8*)(BWd0 + row * 128 + col8);
    *(bf16x8*)(BWD1L + row * 136 + col8) = *(const bf16x8*)(BWd1 + row * 128 + col8);
  }
  // zero AH + A0H + A1 (contiguous span)
  {
    __bf16* z = (__bf16*)(smem + S_AH);
    for (int i = tid; i < 7680; i += 512) z[i] = (__bf16)0.f;
  }
  if (tid < 16) {
    float s = 0.f;
    for (int t = 0; t < 64; ++t) s += hmask[(b0 + tid) * 64 + t];
    s = fminf(fmaxf(s, 1.f), 64.f);
    lastL[tid] = (int)s - 1;
  }

  // per-wave constants
  float bz0r[3], bz1r[3];
#pragma unroll
  for (int g = 0; g < 3; ++g) {
    bz0r[g] = bz0[g * 128 + nc];
    bz1r[g] = bx[(5 + g) * 128 + nc];
  }
  const float bd0r = bd[nc],      bd1r = bd[128 + nc];
  const float wt0r = Wt[nc],      wt1r = Wt[128 + nc];
  const float bt0r = bt[nc],      bt1r = bt[128 + nc];

  // gate weights in registers (unified VGPR/AGPR file)
  bf16x8 wf0[15], wf1[24];
#pragma unroll
  for (int g = 0; g < 3; ++g)
#pragma unroll
    for (int kk = 0; kk < 5; ++kk)
      wf0[g * 5 + kk] = *(const bf16x8*)(BT0 + (g * 128 + nc) * 160 + kk * 32 + q8);
#pragma unroll
  for (int g = 0; g < 3; ++g)
#pragma unroll
    for (int kk = 0; kk < 8; ++kk)
      wf1[g * 8 + kk] = *(const bf16x8*)(BT1 + (g * 128 + nc) * 256 + kk * 32 + q8);

  float h0r[4] = {}, c0r[4] = {}, h1r[4] = {}, c1r[4] = {}, encr[4] = {};

  const int srow = (tid >> 4) & 15, scol = tid & 15;   // staging/head map (tid<256)
  const float* histrow = hist + (long)(b0 + srow) * 1024 + scol;
  const float* hmrow   = hmask + (long)(b0 + srow) * 64;

  // stage t=0 into slot 0; prefetch t=1
  float hv = 0.f, mv = 0.f;
  if (tid < 256) {
    float v0 = histrow[0];
    AH[0][srow][scol] = (__bf16)v0;
    if (scol == 5)
      dmL[0][0][srow] = __fdividef(1.f, __logf(2.7182818284590452f + fmaxf(v0, 0.f)));
    if (scol == 0) dmL[0][1][srow] = hmrow[0];
    hv = histrow[16];
    mv = hmrow[1];
  }
  __syncthreads();

  int lrow[4];
#pragma unroll
  for (int r = 0; r < 4; ++r) lrow[r] = lastL[q * 4 + r];

  // pipelined loop: iteration t runs L0(t) and L1(t-1); t=64 drains L1(63).
  for (int t = 0; t <= 64; ++t) {
    const int p = t & 1, pn = p ^ 1;

    // ================= interval I1: gates =================
    // snapshot d/m(t-1) for the I2 L1-update (slot pn is overwritten in I2)
    float dpre[4], mpre[4];
    if (t > 0) {
#pragma unroll
      for (int r = 0; r < 4; ++r) {
        dpre[r] = dmL[pn][0][q * 4 + r];
        mpre[r] = dmL[pn][1][q * 4 + r];
      }
    }

    float htl0[4], otl0[4], htl1[4], otl1[4];
    if (t < 64) {   // L0 gates(t): z = [hist|0|h0] @ wf0 (K=160)
      f32x4 acc[3];
#pragma unroll
      for (int g = 0; g < 3; ++g) acc[g] = (f32x4){bz0r[g], bz0r[g], bz0r[g], bz0r[g]};
      {
        bf16x8 a = *(const bf16x8*)&AH[p][c16][q8];
#pragma unroll
        for (int g = 0; g < 3; ++g) acc[g] = mfma16(a, wf0[g * 5], acc[g]);
      }
#pragma unroll
      for (int kk = 1; kk < 5; ++kk) {
        bf16x8 a = *(const bf16x8*)&A0H[c16][(kk - 1) * 32 + q8];
#pragma unroll
        for (int g = 0; g < 3; ++g) acc[g] = mfma16(a, wf0[g * 5 + kk], acc[g]);
      }
#pragma unroll
      for (int r = 0; r < 4; ++r) {
        float ht = tanhfast(acc[2][r]) + sigmf(acc[0][r]);
        htl0[r] = ht;
        otl0[r] = sigmf(acc[1][r]);
        AT0[q * 4 + r][nc] = (__bf16)ht;
      }
    }
    if (t > 0) {    // L1 gates(t-1): z = [h0(t-1)|h1(t-2)] @ wf1 (K=256)
      f32x4 acc[3];
#pragma unroll
      for (int g = 0; g < 3; ++g) acc[g] = (f32x4){bz1r[g], bz1r[g], bz1r[g], bz1r[g]};
#pragma unroll
      for (int kk = 0; kk < 8; ++kk) {
        bf16x8 a = *(const bf16x8*)&A1[c16][kk * 32 + q8];
#pragma unroll
        for (int g = 0; g < 3; ++g) acc[g] = mfma16(a, wf1[g * 8 + kk], acc[g]);
      }
#pragma unroll
      for (int r = 0; r < 4; ++r) {
        float ht = tanhfast(acc[2][r]) + sigmf(acc[0][r]);
        htl1[r] = ht;
        otl1[r] = sigmf(acc[1][r]);
        AT1[q * 4 + r][nc] = (__bf16)ht;
      }
    }
    __syncthreads();   // B1

    // ================= interval I2: Wd + state update =================
    if (t < 64) {   // L0 Wd + update(t)
      float drow[4], mrow[4];
#pragma unroll
      for (int r = 0; r < 4; ++r) {
        drow[r] = dmL[p][0][q * 4 + r];
        mrow[r] = dmL[p][1][q * 4 + r];
      }
      f32x4 accd = (f32x4){bd0r, bd0r, bd0r, bd0r};
#pragma unroll
      for (int kk = 0; kk < 4; ++kk) {
        bf16x8 a = *(const bf16x8*)&AT0[c16][kk * 32 + q8];
        bf16x8 b = *(const bf16x8*)(BWD0L + nc * 136 + kk * 32 + q8);
        accd = mfma16(a, b, accd);
      }
#pragma unroll
      for (int r = 0; r < 4; ++r) {
        float hs    = tanhfast(accd[r]);
        float dgate = sigmf(drow[r] * wt0r + bt0r);
        float hstar = htl0[r] + hs * (dgate - 1.f);
        float cn    = tanhfast(hstar + otl0[r] * c0r[r]);
        float hn    = otl0[r] * tanhfast(cn);
        float m     = mrow[r];
        float hl    = m * hn + (1.f - m) * h0r[r];
        float cl    = m * cn + (1.f - m) * c0r[r];
        h0r[r] = hl; c0r[r] = cl;
        __bf16 hb = (__bf16)hl;
        int row = q * 4 + r;
        A0H[row][nc] = hb;
        A1[row][nc]  = hb;
      }
    }
    if (t > 0) {    // L1 Wd + update(t-1)
      f32x4 accd = (f32x4){bd1r, bd1r, bd1r, bd1r};
#pragma unroll
      for (int kk = 0; kk < 4; ++kk) {
        bf16x8 a = *(const bf16x8*)&AT1[c16][kk * 32 + q8];
        bf16x8 b = *(const bf16x8*)(BWD1L + nc * 136 + kk * 32 + q8);
        accd = mfma16(a, b, accd);
      }
      const int tm1 = t - 1;
#pragma unroll
      for (int r = 0; r < 4; ++r) {
        float hs    = tanhfast(accd[r]);
        float dgate = sigmf(dpre[r] * wt1r + bt1r);
        float hstar = htl1[r] + hs * (dgate - 1.f);
        float cn    = tanhfast(hstar + otl1[r] * c1r[r]);
        float hn    = otl1[r] * tanhfast(cn);
        float m     = mpre[r];
        float hl    = m * hn + (1.f - m) * h1r[r];
        float cl    = m * cn + (1.f - m) * c1r[r];
        h1r[r] = hl; c1r[r] = cl;
        A1[q * 4 + r][128 + nc] = (__bf16)hl;
        if (tm1 == lrow[r]) encr[r] = hl * m;
      }
    }
    // stage t+1 into slot pn (its last readers finished in I1, behind B1)
    if (tid < 256 && t < 63) {
      AH[pn][srow][scol] = (__bf16)hv;
      if (scol == 5)
        dmL[pn][0][srow] = __fdividef(1.f, __logf(2.7182818284590452f + fmaxf(hv, 0.f)));
      if (scol == 0) dmL[pn][1][srow] = mv;
      if (t < 62) { hv = histrow[(t + 2) * 16]; mv = hmrow[t + 2]; }
    }
    __syncthreads();   // B2
  }

  // ---- decoder head: state = [hist[b,last,:16] | enc128]; LN; FC-ReLU-FC ----
  if (tid < 256)
    stateL[srow][scol] = hist[((long)(b0 + srow) * 64 + lastL[srow]) * 16 + scol];
#pragma unroll
  for (int r = 0; r < 4; ++r)
    stateL[q * 4 + r][16 + nc] = encr[r];
  __syncthreads();

  if (tid < 256) {
    float sm = 0.f, sq = 0.f;
    for (int k = scol; k < 144; k += 16) {
      float v = stateL[srow][k];
      sm += v; sq += v * v;
    }
    redS[srow][scol] = sm; redQ[srow][scol] = sq;
  }
  __syncthreads();
  if (tid < 16) {
    float sm = 0.f, sq = 0.f;
    for (int s2 = 0; s2 < 16; ++s2) { sm += redS[tid][s2]; sq += redQ[tid][s2]; }
    float mu  = sm * (1.f / 144.f);
    float var = sq * (1.f / 144.f) - mu * mu;
    redS[0][tid] = mu;
    redQ[0][tid] = rsqrtf(var + 1e-5f);
  }
  __syncthreads();
  if (tid < 256) {
    float mu = redS[0][srow], rs = redQ[0][srow];
    for (int k = scol; k < 144; k += 16)
      stateL[srow][k] = (stateL[srow][k] - mu) * rs * lng[k] + lnb[k];
  }
  __syncthreads();
  if (tid < 256) {
    float accw[8];
#pragma unroll
    for (int o = 0; o < 8; ++o) accw[o] = b1[scol + 16 * o];
    for (int k = 0; k < 144; ++k) {
      float sv = stateL[srow][k];
      const float* w = W1 + k * 128 + scol;
#pragma unroll
      for (int o = 0; o < 8; ++o) accw[o] += sv * w[16 * o];
    }
#pragma unroll
    for (int o = 0; o < 8; ++o) a1L[srow][scol + 16 * o] = fmaxf(accw[o], 0.f);
  }
  __syncthreads();
  for (int e = tid; e < 960; e += 512) {
    int row = e / 60, j = e - row * 60;
    float accv = b2[j];
    for (int k = 0; k < 128; ++k) accv += a1L[row][k] * W2[k * 60 + j];
    accv = (accv != accv) ? 0.f : fminf(fmaxf(accv, -1e4f), 1e4f);  // nan_to_num
    out[(b0 + row) * 60 + j] = accv;
  }
}

extern "C" void kernel_launch(void* const* d_in, const int* in_sizes, int n_in,
                              void* d_out, int out_size, void* d_ws, size_t ws_size,
                              hipStream_t stream) {
  const float* hist  = (const float*)d_in[0];
  const float* hmask = (const float*)d_in[1];
  const float* Wp    = (const float*)d_in[2];
  const float* bp    = (const float*)d_in[3];
  const float* Wx    = (const float*)d_in[4];
  const float* bx    = (const float*)d_in[5];
  const float* Uh    = (const float*)d_in[6];
  const float* Wd    = (const float*)d_in[7];
  const float* bd    = (const float*)d_in[8];
  const float* Wt    = (const float*)d_in[9];
  const float* bt    = (const float*)d_in[10];
  const float* lng   = (const float*)d_in[11];
  const float* lnb   = (const float*)d_in[12];
  const float* W1    = (const float*)d_in[13];
  const float* b1    = (const float*)d_in[14];
  const float* W2    = (const float*)d_in[15];
  const float* b2    = (const float*)d_in[16];
  float* out = (float*)d_out;

  char* ws = (char*)d_ws;
  __bf16* BT0  = (__bf16*)ws;
  __bf16* BWd0 = (__bf16*)(ws + OFF_BWD0);
  __bf16* BT1  = (__bf16*)(ws + OFF_BT1);
  __bf16* BWd1 = (__bf16*)(ws + OFF_BWD1);
  float*  bz0  = (float*)(ws + OFF_BZ0);

  hipFuncSetAttribute((const void*)tlstm_main,
                      hipFuncAttributeMaxDynamicSharedMemorySize, S_TOTAL);

  tlstm_fold<<<26, 256, 0, stream>>>(Wp, bp, Wx, bx, BT0, bz0);
  tlstm_pack<<<704, 256, 0, stream>>>(Wx, Uh, Wd, BT0, BWd0, BT1, BWd1);
  tlstm_main<<<256, 512, S_TOTAL, stream>>>(hist, hmask, BT0, BWd0, BT1, BWd1,
                                            bz0, bx, bd, Wt, bt, lng, lnb,
                                            W1, b1, W2, b2, out);
}

// Round 6
// 494.347 us; speedup vs baseline: 1.0173x; 1.0173x over previous
//
#include <hip/hip_runtime.h>
#include <hip/hip_bf16.h>

// TLSTM forecaster. R6 = R5's 2-barrier lagged L0/L1 pipeline + R4's proven
// no-spill weight placement: BT0 in LDS (129KB, stride 168), wf1(24)+bwd(8)
// = 32 frags in registers. B=4096, L=64, D=16, H=128, NL=2.
// grid=256 x 512 thr; block owns 16 batch rows; wave owns 16 N-cols.
// Gate order [i, o, c] (reference's f-gate is dead code).
//
// MFMA 16x16x32 bf16 layouts:
//   A[m=lane&15][k=(lane>>4)*8+j]   B[k][n=lane&15] (packed BT[n][k])
//   D[row=(lane>>4)*4+r][col=lane&15]

typedef __bf16 bf16x8 __attribute__((ext_vector_type(8)));
typedef float  f32x4  __attribute__((ext_vector_type(4)));

__device__ __forceinline__ f32x4 mfma16(bf16x8 a, bf16x8 b, f32x4 c) {
  return __builtin_amdgcn_mfma_f32_16x16x32_bf16(a, b, c, 0, 0, 0);
}
__device__ __forceinline__ float sigmf(float x) {
  return __fdividef(1.f, 1.f + __expf(-x));
}
__device__ __forceinline__ float tanhfast(float x) {
  return 1.f - __fdividef(2.f, 1.f + __expf(2.f * x));
}

// ---------------- ws layout (bytes) ----------------
// BT0p : [384][168] bf16 @ 0        (k 0..15 = Wp@Wx0 fold, 16..31 zeros, 32..159 Uh0)
// BWd0 : [128][128] bf16 @ 129024
// BT1  : [384][256] bf16 @ 161792   (k 0..127 = Wx1, 128..255 = Uh1)
// BWd1 : [128][128] bf16 @ 358400
// bz0  : [384] f32       @ 391168
#define OFF_BWD0 129024
#define OFF_BT1  161792
#define OFF_BWD1 358400
#define OFF_BZ0  391168

// ---------------- dynamic LDS layout (bytes) ----------------
#define S_WB0   0        // [384][168] bf16 = 129024
#define S_AH    129024   // [2][16][40] bf16 = 2560 (cols 16..31 zero)
#define S_A0H   131584   // [16][136] bf16 = 4352 (h0)
#define S_A1    135936   // [16][264] bf16 = 8448 ([h0_new | h1])
#define S_AT0   144384   // [16][136] bf16 = 4352
#define S_AT1   148736   // [16][136] bf16 = 4352
#define S_DM    153088   // [2][2][16] f32 = 256
#define S_LAST  153344   // [16] int
#define S_TOTAL 153408
// head-stage aliases (over WB0; all weight reads done by then):
#define S_STATE 0        // [16][144] f32 = 9216
#define S_A1L   9216     // [16][128] f32 = 8192
#define S_REDS  17408    // [16][16] f32
#define S_REDQ  18432    // [16][16] f32

__global__ void tlstm_fold(const float* __restrict__ Wp, const float* __restrict__ bp,
                           const float* __restrict__ Wx, const float* __restrict__ bx,
                           __bf16* __restrict__ BT0, float* __restrict__ bz0) {
  int idx = blockIdx.x * 256 + threadIdx.x;
  if (idx >= 384 * 17) return;
  int n = idx / 17, kk = idx % 17;
  int npr = n & 127, gs = (n >> 7) + 1;                    // src gates 1,2,3 = i,o,c
  const float* wxcol = Wx + (gs * 128) * 128 + npr;        // Wx[0][gs][h][npr]
  if (kk < 16) {
    const float* wprow = Wp + kk * 128;
    float s = 0.f;
    for (int h = 0; h < 128; ++h) s += wprow[h] * wxcol[h * 128];
    BT0[n * 168 + kk] = (__bf16)s;
  } else {
    float s = bx[gs * 128 + npr];
    for (int h = 0; h < 128; ++h) s += bp[h] * wxcol[h * 128];
    bz0[n] = s;
    for (int k2 = 16; k2 < 32; ++k2) BT0[n * 168 + k2] = (__bf16)0.f;  // zero K-pad
  }
}

__global__ void tlstm_pack(const float* __restrict__ Wx, const float* __restrict__ Uh,
                           const float* __restrict__ Wd,
                           __bf16* __restrict__ BT0, __bf16* __restrict__ BWd0,
                           __bf16* __restrict__ BT1, __bf16* __restrict__ BWd1) {
  int e = blockIdx.x * 256 + threadIdx.x;
  if (e < 49152) {                                  // BT0 Uh0 region
    int n = e >> 7, k = e & 127, npr = n & 127, gs = (n >> 7) + 1;
    BT0[n * 168 + 32 + k] = (__bf16)Uh[(gs * 128 + k) * 128 + npr];
  } else if (e < 65536) {                           // BWd0
    int e2 = e - 49152; int n = e2 >> 7, k = e2 & 127;
    BWd0[n * 128 + k] = (__bf16)Wd[k * 128 + n];
  } else if (e < 163840) {                          // BT1 = [Wx1 ; Uh1]
    int e2 = e - 65536; int n = e2 >> 8, k = e2 & 255;
    int npr = n & 127, gs = (n >> 7) + 1;
    float v = (k < 128) ? Wx[((4 + gs) * 128 + k) * 128 + npr]
                        : Uh[((4 + gs) * 128 + (k - 128)) * 128 + npr];
    BT1[n * 256 + k] = (__bf16)v;
  } else if (e < 180224) {                          // BWd1
    int e2 = e - 163840; int n = e2 >> 7, k = e2 & 127;
    BWd1[n * 128 + k] = (__bf16)Wd[(128 + k) * 128 + n];
  }
}

__global__ __launch_bounds__(512, 1) void tlstm_main(
    const float* __restrict__ hist, const float* __restrict__ hmask,
    const __bf16* __restrict__ BT0, const __bf16* __restrict__ BWd0,
    const __bf16* __restrict__ BT1, const __bf16* __restrict__ BWd1,
    const float* __restrict__ bz0, const float* __restrict__ bx,
    const float* __restrict__ bd, const float* __restrict__ Wt,
    const float* __restrict__ bt, const float* __restrict__ lng,
    const float* __restrict__ lnb, const float* __restrict__ W1,
    const float* __restrict__ b1, const float* __restrict__ W2,
    const float* __restrict__ b2, float* __restrict__ out) {
  extern __shared__ __align__(16) char smem[];
  __bf16* WB0 = (__bf16*)(smem + S_WB0);
  __bf16 (*AH)[16][40]  = (__bf16(*)[16][40])(smem + S_AH);
  __bf16 (*A0H)[136]    = (__bf16(*)[136])(smem + S_A0H);
  __bf16 (*A1)[264]     = (__bf16(*)[264])(smem + S_A1);
  __bf16 (*AT0)[136]    = (__bf16(*)[136])(smem + S_AT0);
  __bf16 (*AT1)[136]    = (__bf16(*)[136])(smem + S_AT1);
  float (*dmL)[2][16]   = (float(*)[2][16])(smem + S_DM);
  int*   lastL          = (int*)(smem + S_LAST);
  float (*stateL)[144]  = (float(*)[144])(smem + S_STATE);
  float (*a1L)[128]     = (float(*)[128])(smem + S_A1L);
  float (*redS)[16]     = (float(*)[16])(smem + S_REDS);
  float (*redQ)[16]     = (float(*)[16])(smem + S_REDQ);

  const int tid  = threadIdx.x;
  const int wave = tid >> 6;
  const int lane = tid & 63;
  const int q    = lane >> 4;
  const int c16  = lane & 15;
  const int q8   = q * 8;
  const int b0   = blockIdx.x * 16;
  const int nc   = wave * 16 + c16;  // owned N-column (0..127)

  // ---- one-time init ----
  for (int i = tid * 8; i < 64512; i += 4096)          // BT0 -> LDS
    *(bf16x8*)(WB0 + i) = *(const bf16x8*)(BT0 + i);
  {
    __bf16* z = (__bf16*)(smem + S_AH);                // zero AH+A0H+A1
    for (int i = tid; i < 7680; i += 512) z[i] = (__bf16)0.f;
  }
  if (tid < 16) {
    float s = 0.f;
    for (int t = 0; t < 64; ++t) s += hmask[(b0 + tid) * 64 + t];
    s = fminf(fmaxf(s, 1.f), 64.f);
    lastL[tid] = (int)s - 1;
  }

  // per-wave constants
  float bz0r[3], bz1r[3];
#pragma unroll
  for (int g = 0; g < 3; ++g) {
    bz0r[g] = bz0[g * 128 + nc];
    bz1r[g] = bx[(5 + g) * 128 + nc];
  }
  const float bd0r = bd[nc],      bd1r = bd[128 + nc];
  const float wt0r = Wt[nc],      wt1r = Wt[128 + nc];
  const float bt0r = bt[nc],      bt1r = bt[128 + nc];

  int offZ0[3];
#pragma unroll
  for (int g = 0; g < 3; ++g) offZ0[g] = (g * 128 + nc) * 168;

  // register weights: wf1 (24) + bwd0/1 (8) = 32 frags (R4-proven no-spill)
  bf16x8 wf1[24], bwd0[4], bwd1[4];
#pragma unroll
  for (int g = 0; g < 3; ++g)
#pragma unroll
    for (int kk = 0; kk < 8; ++kk)
      wf1[g * 8 + kk] = *(const bf16x8*)(BT1 + (g * 128 + nc) * 256 + kk * 32 + q8);
#pragma unroll
  for (int kk = 0; kk < 4; ++kk) {
    bwd0[kk] = *(const bf16x8*)(BWd0 + nc * 128 + q8 + kk * 32);
    bwd1[kk] = *(const bf16x8*)(BWd1 + nc * 128 + q8 + kk * 32);
  }

  float h0r[4] = {}, c0r[4] = {}, h1r[4] = {}, c1r[4] = {}, encr[4] = {};

  const int srow = (tid >> 4) & 15, scol = tid & 15;   // staging/head map (tid<256)
  const float* histrow = hist + (long)(b0 + srow) * 1024 + scol;
  const float* hmrow   = hmask + (long)(b0 + srow) * 64;

  // stage t=0 into slot 0; prefetch t=1
  float hv = 0.f, mv = 0.f;
  if (tid < 256) {
    float v0 = histrow[0];
    AH[0][srow][scol] = (__bf16)v0;
    if (scol == 5)
      dmL[0][0][srow] = __fdividef(1.f, __logf(2.7182818284590452f + fmaxf(v0, 0.f)));
    if (scol == 0) dmL[0][1][srow] = hmrow[0];
    hv = histrow[16];
    mv = hmrow[1];
  }
  __syncthreads();

  int lrow[4];
#pragma unroll
  for (int r = 0; r < 4; ++r) lrow[r] = lastL[q * 4 + r];

  // pipelined loop: iteration t runs L0(t) and L1(t-1); t=64 drains L1(63).
  for (int t = 0; t <= 64; ++t) {
    const int p = t & 1, pn = p ^ 1;

    // snapshot d/m(t-1) for the I2 L1-update (slot pn gets overwritten in I2)
    float dpre[4], mpre[4];
    if (t > 0) {
#pragma unroll
      for (int r = 0; r < 4; ++r) {
        dpre[r] = dmL[pn][0][q * 4 + r];
        mpre[r] = dmL[pn][1][q * 4 + r];
      }
    }

    // ================= interval I1: gates =================
    float htl0[4], otl0[4], htl1[4], otl1[4];
    if (t < 64) {   // L0 gates(t): z = [hist|0|h0] @ WB0 (K=160)
      f32x4 acc[3];
#pragma unroll
      for (int g = 0; g < 3; ++g) acc[g] = (f32x4){bz0r[g], bz0r[g], bz0r[g], bz0r[g]};
      {
        bf16x8 a = *(const bf16x8*)&AH[p][c16][q8];
#pragma unroll
        for (int g = 0; g < 3; ++g)
          acc[g] = mfma16(a, *(const bf16x8*)(WB0 + offZ0[g] + q8), acc[g]);
      }
#pragma unroll
      for (int kk = 0; kk < 4; ++kk) {
        bf16x8 a = *(const bf16x8*)&A0H[c16][kk * 32 + q8];
#pragma unroll
        for (int g = 0; g < 3; ++g)
          acc[g] = mfma16(a, *(const bf16x8*)(WB0 + offZ0[g] + 32 + kk * 32 + q8), acc[g]);
      }
#pragma unroll
      for (int r = 0; r < 4; ++r) {
        float ht = tanhfast(acc[2][r]) + sigmf(acc[0][r]);
        htl0[r] = ht;
        otl0[r] = sigmf(acc[1][r]);
        AT0[q * 4 + r][nc] = (__bf16)ht;
      }
    }
    if (t > 0) {    // L1 gates(t-1): z = [h0(t-1)|h1(t-2)] @ wf1 (K=256)
      f32x4 acc[3];
#pragma unroll
      for (int g = 0; g < 3; ++g) acc[g] = (f32x4){bz1r[g], bz1r[g], bz1r[g], bz1r[g]};
#pragma unroll
      for (int kk = 0; kk < 8; ++kk) {
        bf16x8 a = *(const bf16x8*)&A1[c16][kk * 32 + q8];
#pragma unroll
        for (int g = 0; g < 3; ++g) acc[g] = mfma16(a, wf1[g * 8 + kk], acc[g]);
      }
#pragma unroll
      for (int r = 0; r < 4; ++r) {
        float ht = tanhfast(acc[2][r]) + sigmf(acc[0][r]);
        htl1[r] = ht;
        otl1[r] = sigmf(acc[1][r]);
        AT1[q * 4 + r][nc] = (__bf16)ht;
      }
    }
    __syncthreads();   // B1

    // ================= interval I2: Wd + state update =================
    if (t < 64) {   // L0 Wd + update(t)
      float drow[4], mrow[4];
#pragma unroll
      for (int r = 0; r < 4; ++r) {
        drow[r] = dmL[p][0][q * 4 + r];
        mrow[r] = dmL[p][1][q * 4 + r];
      }
      f32x4 accd = (f32x4){bd0r, bd0r, bd0r, bd0r};
#pragma unroll
      for (int kk = 0; kk < 4; ++kk) {
        bf16x8 a = *(const bf16x8*)&AT0[c16][kk * 32 + q8];
        accd = mfma16(a, bwd0[kk], accd);
      }
#pragma unroll
      for (int r = 0; r < 4; ++r) {
        float hs    = tanhfast(accd[r]);
        float dgate = sigmf(drow[r] * wt0r + bt0r);
        float hstar = htl0[r] + hs * (dgate - 1.f);
        float cn    = tanhfast(hstar + otl0[r] * c0r[r]);
        float hn    = otl0[r] * tanhfast(cn);
        float m     = mrow[r];
        float hl    = m * hn + (1.f - m) * h0r[r];
        float cl    = m * cn + (1.f - m) * c0r[r];
        h0r[r] = hl; c0r[r] = cl;
        __bf16 hb = (__bf16)hl;
        int row = q * 4 + r;
        A0H[row][nc] = hb;
        A1[row][nc]  = hb;
      }
    }
    if (t > 0) {    // L1 Wd + update(t-1)
      f32x4 accd = (f32x4){bd1r, bd1r, bd1r, bd1r};
#pragma unroll
      for (int kk = 0; kk < 4; ++kk) {
        bf16x8 a = *(const bf16x8*)&AT1[c16][kk * 32 + q8];
        accd = mfma16(a, bwd1[kk], accd);
      }
      const int tm1 = t - 1;
#pragma unroll
      for (int r = 0; r < 4; ++r) {
        float hs    = tanhfast(accd[r]);
        float dgate = sigmf(dpre[r] * wt1r + bt1r);
        float hstar = htl1[r] + hs * (dgate - 1.f);
        float cn    = tanhfast(hstar + otl1[r] * c1r[r]);
        float hn    = otl1[r] * tanhfast(cn);
        float m     = mpre[r];
        float hl    = m * hn + (1.f - m) * h1r[r];
        float cl    = m * cn + (1.f - m) * c1r[r];
        h1r[r] = hl; c1r[r] = cl;
        A1[q * 4 + r][128 + nc] = (__bf16)hl;
        if (tm1 == lrow[r]) encr[r] = hl * m;
      }
    }
    // stage t+1 into slot pn (its last readers finished in I1, behind B1)
    if (tid < 256 && t < 63) {
      AH[pn][srow][scol] = (__bf16)hv;
      if (scol == 5)
        dmL[pn][0][srow] = __fdividef(1.f, __logf(2.7182818284590452f + fmaxf(hv, 0.f)));
      if (scol == 0) dmL[pn][1][srow] = mv;
      if (t < 62) { hv = histrow[(t + 2) * 16]; mv = hmrow[t + 2]; }
    }
    __syncthreads();   // B2
  }

  // ---- decoder head: state = [hist[b,last,:16] | enc128]; LN; FC-ReLU-FC ----
  if (tid < 256)
    stateL[srow][scol] = hist[((long)(b0 + srow) * 64 + lastL[srow]) * 16 + scol];
#pragma unroll
  for (int r = 0; r < 4; ++r)
    stateL[q * 4 + r][16 + nc] = encr[r];
  __syncthreads();

  if (tid < 256) {
    float sm = 0.f, sq = 0.f;
    for (int k = scol; k < 144; k += 16) {
      float v = stateL[srow][k];
      sm += v; sq += v * v;
    }
    redS[srow][scol] = sm; redQ[srow][scol] = sq;
  }
  __syncthreads();
  if (tid < 16) {
    float sm = 0.f, sq = 0.f;
    for (int s2 = 0; s2 < 16; ++s2) { sm += redS[tid][s2]; sq += redQ[tid][s2]; }
    float mu  = sm * (1.f / 144.f);
    float var = sq * (1.f / 144.f) - mu * mu;
    redS[0][tid] = mu;
    redQ[0][tid] = rsqrtf(var + 1e-5f);
  }
  __syncthreads();
  if (tid < 256) {
    float mu = redS[0][srow], rs = redQ[0][srow];
    for (int k = scol; k < 144; k += 16)
      stateL[srow][k] = (stateL[srow][k] - mu) * rs * lng[k] + lnb[k];
  }
  __syncthreads();
  if (tid < 256) {
    float accw[8];
#pragma unroll
    for (int o = 0; o < 8; ++o) accw[o] = b1[scol + 16 * o];
    for (int k = 0; k < 144; ++k) {
      float sv = stateL[srow][k];
      const float* w = W1 + k * 128 + scol;
#pragma unroll
      for (int o = 0; o < 8; ++o) accw[o] += sv * w[16 * o];
    }
#pragma unroll
    for (int o = 0; o < 8; ++o) a1L[srow][scol + 16 * o] = fmaxf(accw[o], 0.f);
  }
  __syncthreads();
  for (int e = tid; e < 960; e += 512) {
    int row = e / 60, j = e - row * 60;
    float accv = b2[j];
    for (int k = 0; k < 128; ++k) accv += a1L[row][k] * W2[k * 60 + j];
    accv = (accv != accv) ? 0.f : fminf(fmaxf(accv, -1e4f), 1e4f);  // nan_to_num
    out[(b0 + row) * 60 + j] = accv;
  }
}

extern "C" void kernel_launch(void* const* d_in, const int* in_sizes, int n_in,
                              void* d_out, int out_size, void* d_ws, size_t ws_size,
                              hipStream_t stream) {
  const float* hist  = (const float*)d_in[0];
  const float* hmask = (const float*)d_in[1];
  const float* Wp    = (const float*)d_in[2];
  const float* bp    = (const float*)d_in[3];
  const float* Wx    = (const float*)d_in[4];
  const float* bx    = (const float*)d_in[5];
  const float* Uh    = (const float*)d_in[6];
  const float* Wd    = (const float*)d_in[7];
  const float* bd    = (const float*)d_in[8];
  const float* Wt    = (const float*)d_in[9];
  const float* bt    = (const float*)d_in[10];
  const float* lng   = (const float*)d_in[11];
  const float* lnb   = (const float*)d_in[12];
  const float* W1    = (const float*)d_in[13];
  const float* b1    = (const float*)d_in[14];
  const float* W2    = (const float*)d_in[15];
  const float* b2    = (const float*)d_in[16];
  float* out = (float*)d_out;

  char* ws = (char*)d_ws;
  __bf16* BT0  = (__bf16*)ws;
  __bf16* BWd0 = (__bf16*)(ws + OFF_BWD0);
  __bf16* BT1  = (__bf16*)(ws + OFF_BT1);
  __bf16* BWd1 = (__bf16*)(ws + OFF_BWD1);
  float*  bz0  = (float*)(ws + OFF_BZ0);

  hipFuncSetAttribute((const void*)tlstm_main,
                      hipFuncAttributeMaxDynamicSharedMemorySize, S_TOTAL);

  tlstm_fold<<<26, 256, 0, stream>>>(Wp, bp, Wx, bx, BT0, bz0);
  tlstm_pack<<<704, 256, 0, stream>>>(Wx, Uh, Wd, BT0, BWd0, BT1, BWd1);
  tlstm_main<<<256, 512, S_TOTAL, stream>>>(hist, hmask, BT0, BWd0, BT1, BWd1,
                                            bz0, bx, bd, Wt, bt, lng, lnb,
                                            W1, b1, W2, b2, out);
}

// Round 7
// 324.700 us; speedup vs baseline: 1.5488x; 1.5225x over previous
//
#include <hip/hip_runtime.h>
#include <hip/hip_bf16.h>

// TLSTM forecaster. R7 = exact R4 phase structure (proven 400us: 3 barriers/step,
// WB0 in LDS stride 168, wf1+bwd in regs) + VALU trims:
//  - exp2-native sigmoid/tanh (1 fewer instr each; ~36 fewer instr/lane/step)
//  - L1 A-operand read split A0H/A1H -> h0 written once (saves 4 ds_write_b16)
// B=4096, L=64, D=16, H=128, NL=2, FUT*MD=60, HEAD_IN=144.
// grid=256 x 512 thr; block owns 16 batch rows; wave owns 16 N-cols.
// Gate order [i, o, c] (reference's f-gate is dead code).
//
// MFMA 16x16x32 bf16 layouts:
//   A[m=lane&15][k=(lane>>4)*8+j]   B[k][n=lane&15] (packed BT[n][k])
//   D[row=(lane>>4)*4+r][col=lane&15]

typedef __bf16 bf16x8 __attribute__((ext_vector_type(8)));
typedef float  f32x4  __attribute__((ext_vector_type(4)));

__device__ __forceinline__ f32x4 mfma16(bf16x8 a, bf16x8 b, f32x4 c) {
  return __builtin_amdgcn_mfma_f32_16x16x32_bf16(a, b, c, 0, 0, 0);
}

#if __has_builtin(__builtin_amdgcn_exp2f)
__device__ __forceinline__ float fexp2(float x) { return __builtin_amdgcn_exp2f(x); }
#else
__device__ __forceinline__ float fexp2(float x) { return exp2f(x); }
#endif
#if __has_builtin(__builtin_amdgcn_rcpf)
__device__ __forceinline__ float frcp(float x) { return __builtin_amdgcn_rcpf(x); }
#else
__device__ __forceinline__ float frcp(float x) { return __fdividef(1.f, x); }
#endif
// sigma(x) = 1/(1+2^(-1.4427x)): mul, exp, add, rcp
__device__ __forceinline__ float sigmf(float x) {
  return frcp(1.f + fexp2(-1.44269504f * x));
}
// tanh(x) = 1 - 2/(1+2^(2.8854x)): mul, exp, add, rcp, fma
__device__ __forceinline__ float tanhfast(float x) {
  return __fmaf_rn(-2.f, frcp(1.f + fexp2(2.88539008f * x)), 1.f);
}

// ---------------- ws layout (bytes) ----------------
// BT0p : [384][168] bf16 @ 0        (k 0..15 = Wp@Wx0 fold, 16..31 zeros, 32..159 Uh0)
// BWd0 : [128][128] bf16 @ 129024
// BT1  : [384][256] bf16 @ 161792   (k 0..127 = Wx1, 128..255 = Uh1)
// BWd1 : [128][128] bf16 @ 358400
// bz0  : [384] f32       @ 391168
#define OFF_BWD0 129024
#define OFF_BT1  161792
#define OFF_BWD1 358400
#define OFF_BZ0  391168

// ---------------- dynamic LDS layout (bytes) ----------------
#define S_WB0   0        // [384][168] bf16 = 129024
#define S_AH    129024   // [2][16][40] bf16 = 2560 (cols 16..31 zero)
#define S_A0H   131584   // [16][136] bf16 = 4352 (h0)
#define S_A1H   135936   // [16][136] bf16 = 4352 (h1)
#define S_ATMP  140288   // [16][136] bf16 = 4352 (h_tilde)
#define S_DEC   144640   // [2][16] f32
#define S_MASK  144896   // [2][16] f32
#define S_LAST  145152   // [16] int
#define S_TOTAL 145216
// head-stage aliases (over WB0; all weight reads done by then):
#define S_STATE 0        // [16][144] f32 = 9216
#define S_A1L   9216     // [16][128] f32 = 8192
#define S_REDS  17408    // [16][16] f32
#define S_REDQ  18432    // [16][16] f32

__global__ void tlstm_fold(const float* __restrict__ Wp, const float* __restrict__ bp,
                           const float* __restrict__ Wx, const float* __restrict__ bx,
                           __bf16* __restrict__ BT0, float* __restrict__ bz0) {
  int idx = blockIdx.x * 256 + threadIdx.x;
  if (idx >= 384 * 17) return;
  int n = idx / 17, kk = idx % 17;
  int npr = n & 127, gs = (n >> 7) + 1;                    // src gates 1,2,3 = i,o,c
  const float* wxcol = Wx + (gs * 128) * 128 + npr;        // Wx[0][gs][h][npr]
  if (kk < 16) {
    const float* wprow = Wp + kk * 128;
    float s = 0.f;
    for (int h = 0; h < 128; ++h) s += wprow[h] * wxcol[h * 128];
    BT0[n * 168 + kk] = (__bf16)s;
  } else {
    float s = bx[gs * 128 + npr];
    for (int h = 0; h < 128; ++h) s += bp[h] * wxcol[h * 128];
    bz0[n] = s;
    for (int k2 = 16; k2 < 32; ++k2) BT0[n * 168 + k2] = (__bf16)0.f;  // zero K-pad
  }
}

__global__ void tlstm_pack(const float* __restrict__ Wx, const float* __restrict__ Uh,
                           const float* __restrict__ Wd,
                           __bf16* __restrict__ BT0, __bf16* __restrict__ BWd0,
                           __bf16* __restrict__ BT1, __bf16* __restrict__ BWd1) {
  int e = blockIdx.x * 256 + threadIdx.x;
  if (e < 49152) {                                  // BT0 Uh0 region
    int n = e >> 7, k = e & 127, npr = n & 127, gs = (n >> 7) + 1;
    BT0[n * 168 + 32 + k] = (__bf16)Uh[(gs * 128 + k) * 128 + npr];
  } else if (e < 65536) {                           // BWd0
    int e2 = e - 49152; int n = e2 >> 7, k = e2 & 127;
    BWd0[n * 128 + k] = (__bf16)Wd[k * 128 + n];
  } else if (e < 163840) {                          // BT1 = [Wx1 ; Uh1]
    int e2 = e - 65536; int n = e2 >> 8, k = e2 & 255;
    int npr = n & 127, gs = (n >> 7) + 1;
    float v = (k < 128) ? Wx[((4 + gs) * 128 + k) * 128 + npr]
                        : Uh[((4 + gs) * 128 + (k - 128)) * 128 + npr];
    BT1[n * 256 + k] = (__bf16)v;
  } else if (e < 180224) {                          // BWd1
    int e2 = e - 163840; int n = e2 >> 7, k = e2 & 127;
    BWd1[n * 128 + k] = (__bf16)Wd[(128 + k) * 128 + n];
  }
}

__global__ __launch_bounds__(512, 1) void tlstm_main(
    const float* __restrict__ hist, const float* __restrict__ hmask,
    const __bf16* __restrict__ BT0, const __bf16* __restrict__ BWd0,
    const __bf16* __restrict__ BT1, const __bf16* __restrict__ BWd1,
    const float* __restrict__ bz0, const float* __restrict__ bx,
    const float* __restrict__ bd, const float* __restrict__ Wt,
    const float* __restrict__ bt, const float* __restrict__ lng,
    const float* __restrict__ lnb, const float* __restrict__ W1,
    const float* __restrict__ b1, const float* __restrict__ W2,
    const float* __restrict__ b2, float* __restrict__ out) {
  extern __shared__ __align__(16) char smem[];
  __bf16* WB0 = (__bf16*)(smem + S_WB0);
  __bf16 (*AH)[16][40]  = (__bf16(*)[16][40])(smem + S_AH);
  __bf16 (*A0H)[136]    = (__bf16(*)[136])(smem + S_A0H);
  __bf16 (*A1H)[136]    = (__bf16(*)[136])(smem + S_A1H);
  __bf16 (*ATMP)[136]   = (__bf16(*)[136])(smem + S_ATMP);
  float (*decayL)[16]   = (float(*)[16])(smem + S_DEC);
  float (*maskL)[16]    = (float(*)[16])(smem + S_MASK);
  int*   lastL          = (int*)(smem + S_LAST);
  float (*stateL)[144]  = (float(*)[144])(smem + S_STATE);
  float (*a1L)[128]     = (float(*)[128])(smem + S_A1L);
  float (*redS)[16]     = (float(*)[16])(smem + S_REDS);
  float (*redQ)[16]     = (float(*)[16])(smem + S_REDQ);

  const int tid  = threadIdx.x;
  const int wave = tid >> 6;
  const int lane = tid & 63;
  const int q    = lane >> 4;
  const int c16  = lane & 15;
  const int q8   = q * 8;
  const int b0   = blockIdx.x * 16;
  const int nc   = wave * 16 + c16;  // owned N-column (0..127)

  // ---- one-time init ----
  for (int i = tid * 8; i < 64512; i += 4096)          // BT0 -> LDS
    *(bf16x8*)(WB0 + i) = *(const bf16x8*)(BT0 + i);
  {
    __bf16* z = (__bf16*)(smem + S_AH);                // zero AH+A0H+A1H+ATMP
    for (int i = tid; i < 7808; i += 512) z[i] = (__bf16)0.f;
  }
  if (tid < 16) {
    float s = 0.f;
    for (int t = 0; t < 64; ++t) s += hmask[(b0 + tid) * 64 + t];
    s = fminf(fmaxf(s, 1.f), 64.f);
    lastL[tid] = (int)s - 1;
  }

  // per-wave constants
  float bz0r[3], bz1r[3];
#pragma unroll
  for (int g = 0; g < 3; ++g) {
    bz0r[g] = bz0[g * 128 + nc];
    bz1r[g] = bx[(5 + g) * 128 + nc];
  }
  const float bd0r = bd[nc],      bd1r = bd[128 + nc];
  const float wt0r = Wt[nc],      wt1r = Wt[128 + nc];
  const float bt0r = bt[nc],      bt1r = bt[128 + nc];

  int offZ0[3];
#pragma unroll
  for (int g = 0; g < 3; ++g) offZ0[g] = (g * 128 + nc) * 168;

  // register weights: wf1 (24) + bwd0/1 (8) = 32 frags (R4-proven no-spill)
  bf16x8 wf1[24], bwd0[4], bwd1[4];
#pragma unroll
  for (int g = 0; g < 3; ++g)
#pragma unroll
    for (int kk = 0; kk < 8; ++kk)
      wf1[g * 8 + kk] = *(const bf16x8*)(BT1 + (g * 128 + nc) * 256 + kk * 32 + q8);
#pragma unroll
  for (int kk = 0; kk < 4; ++kk) {
    bwd0[kk] = *(const bf16x8*)(BWd0 + nc * 128 + q8 + kk * 32);
    bwd1[kk] = *(const bf16x8*)(BWd1 + nc * 128 + q8 + kk * 32);
  }

  float h0r[4] = {}, c0r[4] = {}, h1r[4] = {}, c1r[4] = {}, encr[4] = {};

  __syncthreads();   // init complete

  int lrow[4];
#pragma unroll
  for (int r = 0; r < 4; ++r) lrow[r] = lastL[q * 4 + r];

  const int srow = (tid >> 4) & 15, scol = tid & 15;   // staging/head map (tid<256)
  const float* histrow = hist + (long)(b0 + srow) * 1024 + scol;
  const float* hmrow   = hmask + (long)(b0 + srow) * 64;

  // stage t=0 into slot 0; prefetch t=1
  float hv = 0.f, mv = 0.f;
  if (tid < 256) {
    float v0 = histrow[0];
    AH[0][srow][scol] = (__bf16)v0;
    if (scol == 5)
      decayL[0][srow] = __fdividef(1.f, __logf(2.7182818284590452f + fmaxf(v0, 0.f)));
    if (scol == 0) maskL[0][srow] = hmrow[0];
    hv = histrow[16];
    mv = hmrow[1];
  }
  __syncthreads();

  for (int t = 0; t < 64; ++t) {
    const int p = t & 1, pn = p ^ 1;
    // ---- stage t+1 into slot pn (readers of pn are >=3 barriers away) ----
    if (tid < 256 && t < 63) {
      AH[pn][srow][scol] = (__bf16)hv;
      if (scol == 5)
        decayL[pn][srow] = __fdividef(1.f, __logf(2.7182818284590452f + fmaxf(hv, 0.f)));
      if (scol == 0) maskL[pn][srow] = mv;
      if (t < 62) { hv = histrow[(t + 2) * 16]; mv = hmrow[t + 2]; }
    }

    float drow[4], mrow[4];
#pragma unroll
    for (int r = 0; r < 4; ++r) {
      drow[r] = decayL[p][q * 4 + r];
      mrow[r] = maskL[p][q * 4 + r];
    }

    // ---- phase A: layer 0 gates, z = [hist|0|h0] @ WB0 (K=160) ----
    f32x4 acc[3];
#pragma unroll
    for (int g = 0; g < 3; ++g) acc[g] = (f32x4){bz0r[g], bz0r[g], bz0r[g], bz0r[g]};
    {
      bf16x8 a = *(const bf16x8*)&AH[p][c16][q8];
#pragma unroll
      for (int g = 0; g < 3; ++g)
        acc[g] = mfma16(a, *(const bf16x8*)(WB0 + offZ0[g] + q8), acc[g]);
    }
#pragma unroll
    for (int kk = 0; kk < 4; ++kk) {
      bf16x8 a = *(const bf16x8*)&A0H[c16][kk * 32 + q8];
#pragma unroll
      for (int g = 0; g < 3; ++g)
        acc[g] = mfma16(a, *(const bf16x8*)(WB0 + offZ0[g] + 32 + kk * 32 + q8), acc[g]);
    }
    float htl[4], otl[4];
#pragma unroll
    for (int r = 0; r < 4; ++r) {
      float ht = tanhfast(acc[2][r]) + sigmf(acc[0][r]);
      htl[r] = ht;
      otl[r] = sigmf(acc[1][r]);
      ATMP[q * 4 + r][nc] = (__bf16)ht;
    }
    __syncthreads();   // (2)

    // ---- phase B: layer 0 Wd + state update (writes h0 -> A0H only) ----
    f32x4 accd = (f32x4){bd0r, bd0r, bd0r, bd0r};
#pragma unroll
    for (int kk = 0; kk < 4; ++kk) {
      bf16x8 a = *(const bf16x8*)&ATMP[c16][kk * 32 + q8];
      accd = mfma16(a, bwd0[kk], accd);
    }
#pragma unroll
    for (int r = 0; r < 4; ++r) {
      float hs    = tanhfast(accd[r]);
      float dgate = sigmf(__fmaf_rn(drow[r], wt0r, bt0r));
      float hstar = __fmaf_rn(hs, dgate - 1.f, htl[r]);
      float cn    = tanhfast(__fmaf_rn(otl[r], c0r[r], hstar));
      float hn    = otl[r] * tanhfast(cn);
      float m     = mrow[r];
      float hl    = __fmaf_rn(m, hn - h0r[r], h0r[r]);
      float cl    = __fmaf_rn(m, cn - c0r[r], c0r[r]);
      h0r[r] = hl; c0r[r] = cl;
      A0H[q * 4 + r][nc] = (__bf16)hl;
    }
    __syncthreads();   // (3)

    // ---- phase C: layer 1 gates, z = [h0|h1] @ wf1 (K=256, A split A0H/A1H) ----
#pragma unroll
    for (int g = 0; g < 3; ++g) acc[g] = (f32x4){bz1r[g], bz1r[g], bz1r[g], bz1r[g]};
#pragma unroll
    for (int kk = 0; kk < 4; ++kk) {
      bf16x8 a = *(const bf16x8*)&A0H[c16][kk * 32 + q8];
#pragma unroll
      for (int g = 0; g < 3; ++g) acc[g] = mfma16(a, wf1[g * 8 + kk], acc[g]);
    }
#pragma unroll
    for (int kk = 4; kk < 8; ++kk) {
      bf16x8 a = *(const bf16x8*)&A1H[c16][(kk - 4) * 32 + q8];
#pragma unroll
      for (int g = 0; g < 3; ++g) acc[g] = mfma16(a, wf1[g * 8 + kk], acc[g]);
    }
#pragma unroll
    for (int r = 0; r < 4; ++r) {
      float ht = tanhfast(acc[2][r]) + sigmf(acc[0][r]);
      htl[r] = ht;
      otl[r] = sigmf(acc[1][r]);
      ATMP[q * 4 + r][nc] = (__bf16)ht;
    }
    __syncthreads();   // (4)

    // ---- phase D: layer 1 Wd + state update + encoded capture ----
    accd = (f32x4){bd1r, bd1r, bd1r, bd1r};
#pragma unroll
    for (int kk = 0; kk < 4; ++kk) {
      bf16x8 a = *(const bf16x8*)&ATMP[c16][kk * 32 + q8];
      accd = mfma16(a, bwd1[kk], accd);
    }
#pragma unroll
    for (int r = 0; r < 4; ++r) {
      float hs    = tanhfast(accd[r]);
      float dgate = sigmf(__fmaf_rn(drow[r], wt1r, bt1r));
      float hstar = __fmaf_rn(hs, dgate - 1.f, htl[r]);
      float cn    = tanhfast(__fmaf_rn(otl[r], c1r[r], hstar));
      float hn    = otl[r] * tanhfast(cn);
      float m     = mrow[r];
      float hl    = __fmaf_rn(m, hn - h1r[r], h1r[r]);
      float cl    = __fmaf_rn(m, cn - c1r[r], c1r[r]);
      h1r[r] = hl; c1r[r] = cl;
      A1H[q * 4 + r][nc] = (__bf16)hl;
      if (t == lrow[r]) encr[r] = hl * m;
    }
    // no barrier: next phase A reads A0H (behind (3)) and AH[pn] (staged, 3 barriers back)
  }

  __syncthreads();   // all WB0 reads done; safe to alias head buffers

  // ---- decoder head: state = [hist[b,last,:16] | enc128]; LN; FC-ReLU-FC ----
  if (tid < 256)
    stateL[srow][scol] = hist[((long)(b0 + srow) * 64 + lastL[srow]) * 16 + scol];
#pragma unroll
  for (int r = 0; r < 4; ++r)
    stateL[q * 4 + r][16 + nc] = encr[r];
  __syncthreads();

  if (tid < 256) {
    float sm = 0.f, sq = 0.f;
    for (int k = scol; k < 144; k += 16) {
      float v = stateL[srow][k];
      sm += v; sq += v * v;
    }
    redS[srow][scol] = sm; redQ[srow][scol] = sq;
  }
  __syncthreads();
  if (tid < 16) {
    float sm = 0.f, sq = 0.f;
    for (int s2 = 0; s2 < 16; ++s2) { sm += redS[tid][s2]; sq += redQ[tid][s2]; }
    float mu  = sm * (1.f / 144.f);
    float var = sq * (1.f / 144.f) - mu * mu;
    redS[0][tid] = mu;
    redQ[0][tid] = rsqrtf(var + 1e-5f);
  }
  __syncthreads();
  if (tid < 256) {
    float mu = redS[0][srow], rs = redQ[0][srow];
    for (int k = scol; k < 144; k += 16)
      stateL[srow][k] = (stateL[srow][k] - mu) * rs * lng[k] + lnb[k];
  }
  __syncthreads();
  if (tid < 256) {
    float accw[8];
#pragma unroll
    for (int o = 0; o < 8; ++o) accw[o] = b1[scol + 16 * o];
    for (int k = 0; k < 144; ++k) {
      float sv = stateL[srow][k];
      const float* w = W1 + k * 128 + scol;
#pragma unroll
      for (int o = 0; o < 8; ++o) accw[o] += sv * w[16 * o];
    }
#pragma unroll
    for (int o = 0; o < 8; ++o) a1L[srow][scol + 16 * o] = fmaxf(accw[o], 0.f);
  }
  __syncthreads();
  for (int e = tid; e < 960; e += 512) {
    int row = e / 60, j = e - row * 60;
    float accv = b2[j];
    for (int k = 0; k < 128; ++k) accv += a1L[row][k] * W2[k * 60 + j];
    accv = (accv != accv) ? 0.f : fminf(fmaxf(accv, -1e4f), 1e4f);  // nan_to_num
    out[(b0 + row) * 60 + j] = accv;
  }
}

extern "C" void kernel_launch(void* const* d_in, const int* in_sizes, int n_in,
                              void* d_out, int out_size, void* d_ws, size_t ws_size,
                              hipStream_t stream) {
  const float* hist  = (const float*)d_in[0];
  const float* hmask = (const float*)d_in[1];
  const float* Wp    = (const float*)d_in[2];
  const float* bp    = (const float*)d_in[3];
  const float* Wx    = (const float*)d_in[4];
  const float* bx    = (const float*)d_in[5];
  const float* Uh    = (const float*)d_in[6];
  const float* Wd    = (const float*)d_in[7];
  const float* bd    = (const float*)d_in[8];
  const float* Wt    = (const float*)d_in[9];
  const float* bt    = (const float*)d_in[10];
  const float* lng   = (const float*)d_in[11];
  const float* lnb   = (const float*)d_in[12];
  const float* W1    = (const float*)d_in[13];
  const float* b1    = (const float*)d_in[14];
  const float* W2    = (const float*)d_in[15];
  const float* b2    = (const float*)d_in[16];
  float* out = (float*)d_out;

  char* ws = (char*)d_ws;
  __bf16* BT0  = (__bf16*)ws;
  __bf16* BWd0 = (__bf16*)(ws + OFF_BWD0);
  __bf16* BT1  = (__bf16*)(ws + OFF_BT1);
  __bf16* BWd1 = (__bf16*)(ws + OFF_BWD1);
  float*  bz0  = (float*)(ws + OFF_BZ0);

  hipFuncSetAttribute((const void*)tlstm_main,
                      hipFuncAttributeMaxDynamicSharedMemorySize, S_TOTAL);

  tlstm_fold<<<26, 256, 0, stream>>>(Wp, bp, Wx, bx, BT0, bz0);
  tlstm_pack<<<704, 256, 0, stream>>>(Wx, Uh, Wd, BT0, BWd0, BT1, BWd1);
  tlstm_main<<<256, 512, S_TOTAL, stream>>>(hist, hmask, BT0, BWd0, BT1, BWd1,
                                            bz0, bx, bd, Wt, bt, lng, lnb,
                                            W1, b1, W2, b2, out);
}

// Round 8
// 316.333 us; speedup vs baseline: 1.5898x; 1.0265x over previous
//
#include <hip/hip_runtime.h>
#include <hip/hip_bf16.h>

// TLSTM forecaster. R8 = R6's 2-barrier lagged L0/L1 pipeline executed on R7's
// lean state (the R5/R6 failures were spill-induced, not structural):
//   I1: L0-gates(t) || L1-gates(t-1)   [two independent GEMM+epilogue chains]
//   I2: L0-update(t) || L1-update(t-1) [ditto]
// WB0 (L0 gate W, 129KB) in LDS stride 168; wf1(24)+bwd(8)=32 frags in regs
// (=128 AGPR, R4/R7-proven no-spill); exp2-native trans; split ATMP0/ATMP1.
// B=4096, L=64, D=16, H=128, NL=2, FUT*MD=60, HEAD_IN=144.
// grid=256 x 512 thr; block owns 16 batch rows; wave owns 16 N-cols.
// Gate order [i, o, c] (reference's f-gate is dead code).
//
// MFMA 16x16x32 bf16 layouts:
//   A[m=lane&15][k=(lane>>4)*8+j]   B[k][n=lane&15] (packed BT[n][k])
//   D[row=(lane>>4)*4+r][col=lane&15]

typedef __bf16 bf16x8 __attribute__((ext_vector_type(8)));
typedef float  f32x4  __attribute__((ext_vector_type(4)));

__device__ __forceinline__ f32x4 mfma16(bf16x8 a, bf16x8 b, f32x4 c) {
  return __builtin_amdgcn_mfma_f32_16x16x32_bf16(a, b, c, 0, 0, 0);
}

#if __has_builtin(__builtin_amdgcn_exp2f)
__device__ __forceinline__ float fexp2(float x) { return __builtin_amdgcn_exp2f(x); }
#else
__device__ __forceinline__ float fexp2(float x) { return exp2f(x); }
#endif
#if __has_builtin(__builtin_amdgcn_rcpf)
__device__ __forceinline__ float frcp(float x) { return __builtin_amdgcn_rcpf(x); }
#else
__device__ __forceinline__ float frcp(float x) { return __fdividef(1.f, x); }
#endif
__device__ __forceinline__ float sigmf(float x) {
  return frcp(1.f + fexp2(-1.44269504f * x));
}
__device__ __forceinline__ float tanhfast(float x) {
  return __fmaf_rn(-2.f, frcp(1.f + fexp2(2.88539008f * x)), 1.f);
}

// ---------------- ws layout (bytes) ----------------
// BT0p : [384][168] bf16 @ 0        (k 0..15 = Wp@Wx0 fold, 16..31 zeros, 32..159 Uh0)
// BWd0 : [128][128] bf16 @ 129024
// BT1  : [384][256] bf16 @ 161792   (k 0..127 = Wx1, 128..255 = Uh1)
// BWd1 : [128][128] bf16 @ 358400
// bz0  : [384] f32       @ 391168
#define OFF_BWD0 129024
#define OFF_BT1  161792
#define OFF_BWD1 358400
#define OFF_BZ0  391168

// ---------------- dynamic LDS layout (bytes) ----------------
#define S_WB0   0        // [384][168] bf16 = 129024
#define S_AH    129024   // [2][16][40] bf16 = 2560 (cols 16..31 zero)
#define S_A0H   131584   // [16][136] bf16 = 4352 (h0)
#define S_A1H   135936   // [16][136] bf16 = 4352 (h1)
#define S_AT0   140288   // [16][136] bf16 = 4352 (h_tilde L0)
#define S_AT1   144640   // [16][136] bf16 = 4352 (h_tilde L1)
#define S_DM    148992   // [2][2][16] f32 = 256
#define S_LAST  149248   // [16] int
#define S_TOTAL 149312
// head-stage aliases (over WB0; all weight reads done by then):
#define S_STATE 0        // [16][144] f32 = 9216
#define S_A1L   9216     // [16][128] f32 = 8192
#define S_REDS  17408    // [16][16] f32
#define S_REDQ  18432    // [16][16] f32

__global__ void tlstm_fold(const float* __restrict__ Wp, const float* __restrict__ bp,
                           const float* __restrict__ Wx, const float* __restrict__ bx,
                           __bf16* __restrict__ BT0, float* __restrict__ bz0) {
  int idx = blockIdx.x * 256 + threadIdx.x;
  if (idx >= 384 * 17) return;
  int n = idx / 17, kk = idx % 17;
  int npr = n & 127, gs = (n >> 7) + 1;                    // src gates 1,2,3 = i,o,c
  const float* wxcol = Wx + (gs * 128) * 128 + npr;        // Wx[0][gs][h][npr]
  if (kk < 16) {
    const float* wprow = Wp + kk * 128;
    float s = 0.f;
    for (int h = 0; h < 128; ++h) s += wprow[h] * wxcol[h * 128];
    BT0[n * 168 + kk] = (__bf16)s;
  } else {
    float s = bx[gs * 128 + npr];
    for (int h = 0; h < 128; ++h) s += bp[h] * wxcol[h * 128];
    bz0[n] = s;
    for (int k2 = 16; k2 < 32; ++k2) BT0[n * 168 + k2] = (__bf16)0.f;  // zero K-pad
  }
}

__global__ void tlstm_pack(const float* __restrict__ Wx, const float* __restrict__ Uh,
                           const float* __restrict__ Wd,
                           __bf16* __restrict__ BT0, __bf16* __restrict__ BWd0,
                           __bf16* __restrict__ BT1, __bf16* __restrict__ BWd1) {
  int e = blockIdx.x * 256 + threadIdx.x;
  if (e < 49152) {                                  // BT0 Uh0 region
    int n = e >> 7, k = e & 127, npr = n & 127, gs = (n >> 7) + 1;
    BT0[n * 168 + 32 + k] = (__bf16)Uh[(gs * 128 + k) * 128 + npr];
  } else if (e < 65536) {                           // BWd0
    int e2 = e - 49152; int n = e2 >> 7, k = e2 & 127;
    BWd0[n * 128 + k] = (__bf16)Wd[k * 128 + n];
  } else if (e < 163840) {                          // BT1 = [Wx1 ; Uh1]
    int e2 = e - 65536; int n = e2 >> 8, k = e2 & 255;
    int npr = n & 127, gs = (n >> 7) + 1;
    float v = (k < 128) ? Wx[((4 + gs) * 128 + k) * 128 + npr]
                        : Uh[((4 + gs) * 128 + (k - 128)) * 128 + npr];
    BT1[n * 256 + k] = (__bf16)v;
  } else if (e < 180224) {                          // BWd1
    int e2 = e - 163840; int n = e2 >> 7, k = e2 & 127;
    BWd1[n * 128 + k] = (__bf16)Wd[(128 + k) * 128 + n];
  }
}

__global__ __launch_bounds__(512, 1) void tlstm_main(
    const float* __restrict__ hist, const float* __restrict__ hmask,
    const __bf16* __restrict__ BT0, const __bf16* __restrict__ BWd0,
    const __bf16* __restrict__ BT1, const __bf16* __restrict__ BWd1,
    const float* __restrict__ bz0, const float* __restrict__ bx,
    const float* __restrict__ bd, const float* __restrict__ Wt,
    const float* __restrict__ bt, const float* __restrict__ lng,
    const float* __restrict__ lnb, const float* __restrict__ W1,
    const float* __restrict__ b1, const float* __restrict__ W2,
    const float* __restrict__ b2, float* __restrict__ out) {
  extern __shared__ __align__(16) char smem[];
  __bf16* WB0 = (__bf16*)(smem + S_WB0);
  __bf16 (*AH)[16][40]  = (__bf16(*)[16][40])(smem + S_AH);
  __bf16 (*A0H)[136]    = (__bf16(*)[136])(smem + S_A0H);
  __bf16 (*A1H)[136]    = (__bf16(*)[136])(smem + S_A1H);
  __bf16 (*AT0)[136]    = (__bf16(*)[136])(smem + S_AT0);
  __bf16 (*AT1)[136]    = (__bf16(*)[136])(smem + S_AT1);
  float (*dmL)[2][16]   = (float(*)[2][16])(smem + S_DM);
  int*   lastL          = (int*)(smem + S_LAST);
  float (*stateL)[144]  = (float(*)[144])(smem + S_STATE);
  float (*a1L)[128]     = (float(*)[128])(smem + S_A1L);
  float (*redS)[16]     = (float(*)[16])(smem + S_REDS);
  float (*redQ)[16]     = (float(*)[16])(smem + S_REDQ);

  const int tid  = threadIdx.x;
  const int wave = tid >> 6;
  const int lane = tid & 63;
  const int q    = lane >> 4;
  const int c16  = lane & 15;
  const int q8   = q * 8;
  const int b0   = blockIdx.x * 16;
  const int nc   = wave * 16 + c16;  // owned N-column (0..127)

  // ---- one-time init ----
  for (int i = tid * 8; i < 64512; i += 4096)          // BT0 -> LDS
    *(bf16x8*)(WB0 + i) = *(const bf16x8*)(BT0 + i);
  {
    __bf16* z = (__bf16*)(smem + S_AH);                // zero AH+A0H+A1H
    for (int i = tid; i < 5632; i += 512) z[i] = (__bf16)0.f;
  }
  if (tid < 16) {
    float s = 0.f;
    for (int t = 0; t < 64; ++t) s += hmask[(b0 + tid) * 64 + t];
    s = fminf(fmaxf(s, 1.f), 64.f);
    lastL[tid] = (int)s - 1;
  }

  // per-wave constants
  float bz0r[3], bz1r[3];
#pragma unroll
  for (int g = 0; g < 3; ++g) {
    bz0r[g] = bz0[g * 128 + nc];
    bz1r[g] = bx[(5 + g) * 128 + nc];
  }
  const float bd0r = bd[nc],      bd1r = bd[128 + nc];
  const float wt0r = Wt[nc],      wt1r = Wt[128 + nc];
  const float bt0r = bt[nc],      bt1r = bt[128 + nc];

  int offZ0[3];
#pragma unroll
  for (int g = 0; g < 3; ++g) offZ0[g] = (g * 128 + nc) * 168;

  // register weights: wf1 (24) + bwd0/1 (8) = 32 frags (proven no-spill)
  bf16x8 wf1[24], bwd0[4], bwd1[4];
#pragma unroll
  for (int g = 0; g < 3; ++g)
#pragma unroll
    for (int kk = 0; kk < 8; ++kk)
      wf1[g * 8 + kk] = *(const bf16x8*)(BT1 + (g * 128 + nc) * 256 + kk * 32 + q8);
#pragma unroll
  for (int kk = 0; kk < 4; ++kk) {
    bwd0[kk] = *(const bf16x8*)(BWd0 + nc * 128 + q8 + kk * 32);
    bwd1[kk] = *(const bf16x8*)(BWd1 + nc * 128 + q8 + kk * 32);
  }

  float h0r[4] = {}, c0r[4] = {}, h1r[4] = {}, c1r[4] = {}, encr[4] = {};

  __syncthreads();   // init complete

  int lrow[4];
#pragma unroll
  for (int r = 0; r < 4; ++r) lrow[r] = lastL[q * 4 + r];

  const int srow = (tid >> 4) & 15, scol = tid & 15;   // staging/head map (tid<256)
  const float* histrow = hist + (long)(b0 + srow) * 1024 + scol;
  const float* hmrow   = hmask + (long)(b0 + srow) * 64;

  // stage t=0 into slot 0; prefetch t=1
  float hv = 0.f, mv = 0.f;
  if (tid < 256) {
    float v0 = histrow[0];
    AH[0][srow][scol] = (__bf16)v0;
    if (scol == 5)
      dmL[0][0][srow] = __fdividef(1.f, __logf(2.7182818284590452f + fmaxf(v0, 0.f)));
    if (scol == 0) dmL[0][1][srow] = hmrow[0];
    hv = histrow[16];
    mv = hmrow[1];
  }
  __syncthreads();

  // lagged pipeline: iter t runs L0(t) and L1(t-1); t=64 drains L1(63).
  for (int t = 0; t <= 64; ++t) {
    const int p = t & 1, pn = p ^ 1;

    // snapshot d/m(t-1) for I2's L1-update (slot pn is re-staged in I2)
    float dpre[4], mpre[4];
    if (t > 0) {
#pragma unroll
      for (int r = 0; r < 4; ++r) {
        dpre[r] = dmL[pn][0][q * 4 + r];
        mpre[r] = dmL[pn][1][q * 4 + r];
      }
    }

    // ================= I1: gate GEMMs (two independent chains) =================
    float htl0[4], otl0[4], htl1[4], otl1[4];
    if (t > 0) {    // L1 gates(t-1): z = [h0(t-1)|h1(t-2)] @ wf1 (K=256, regs)
      f32x4 acc[3];
#pragma unroll
      for (int g = 0; g < 3; ++g) acc[g] = (f32x4){bz1r[g], bz1r[g], bz1r[g], bz1r[g]};
#pragma unroll
      for (int kk = 0; kk < 4; ++kk) {
        bf16x8 a = *(const bf16x8*)&A0H[c16][kk * 32 + q8];
#pragma unroll
        for (int g = 0; g < 3; ++g) acc[g] = mfma16(a, wf1[g * 8 + kk], acc[g]);
      }
#pragma unroll
      for (int kk = 4; kk < 8; ++kk) {
        bf16x8 a = *(const bf16x8*)&A1H[c16][(kk - 4) * 32 + q8];
#pragma unroll
        for (int g = 0; g < 3; ++g) acc[g] = mfma16(a, wf1[g * 8 + kk], acc[g]);
      }
#pragma unroll
      for (int r = 0; r < 4; ++r) {
        float ht = tanhfast(acc[2][r]) + sigmf(acc[0][r]);
        htl1[r] = ht;
        otl1[r] = sigmf(acc[1][r]);
        AT1[q * 4 + r][nc] = (__bf16)ht;
      }
    }
    if (t < 64) {   // L0 gates(t): z = [hist|0|h0(t-1)] @ WB0 (K=160, LDS)
      f32x4 acc[3];
#pragma unroll
      for (int g = 0; g < 3; ++g) acc[g] = (f32x4){bz0r[g], bz0r[g], bz0r[g], bz0r[g]};
      {
        bf16x8 a = *(const bf16x8*)&AH[p][c16][q8];
#pragma unroll
        for (int g = 0; g < 3; ++g)
          acc[g] = mfma16(a, *(const bf16x8*)(WB0 + offZ0[g] + q8), acc[g]);
      }
#pragma unroll
      for (int kk = 0; kk < 4; ++kk) {
        bf16x8 a = *(const bf16x8*)&A0H[c16][kk * 32 + q8];
#pragma unroll
        for (int g = 0; g < 3; ++g)
          acc[g] = mfma16(a, *(const bf16x8*)(WB0 + offZ0[g] + 32 + kk * 32 + q8), acc[g]);
      }
#pragma unroll
      for (int r = 0; r < 4; ++r) {
        float ht = tanhfast(acc[2][r]) + sigmf(acc[0][r]);
        htl0[r] = ht;
        otl0[r] = sigmf(acc[1][r]);
        AT0[q * 4 + r][nc] = (__bf16)ht;
      }
    }
    __syncthreads();   // B1

    // ================= I2: Wd GEMMs + state updates =================
    if (t < 64) {   // L0 update(t): writes h0(t) -> A0H
      float drow[4], mrow[4];
#pragma unroll
      for (int r = 0; r < 4; ++r) {
        drow[r] = dmL[p][0][q * 4 + r];
        mrow[r] = dmL[p][1][q * 4 + r];
      }
      f32x4 accd = (f32x4){bd0r, bd0r, bd0r, bd0r};
#pragma unroll
      for (int kk = 0; kk < 4; ++kk) {
        bf16x8 a = *(const bf16x8*)&AT0[c16][kk * 32 + q8];
        accd = mfma16(a, bwd0[kk], accd);
      }
#pragma unroll
      for (int r = 0; r < 4; ++r) {
        float hs    = tanhfast(accd[r]);
        float dgate = sigmf(__fmaf_rn(drow[r], wt0r, bt0r));
        float hstar = __fmaf_rn(hs, dgate - 1.f, htl0[r]);
        float cn    = tanhfast(__fmaf_rn(otl0[r], c0r[r], hstar));
        float hn    = otl0[r] * tanhfast(cn);
        float m     = mrow[r];
        float hl    = __fmaf_rn(m, hn - h0r[r], h0r[r]);
        float cl    = __fmaf_rn(m, cn - c0r[r], c0r[r]);
        h0r[r] = hl; c0r[r] = cl;
        A0H[q * 4 + r][nc] = (__bf16)hl;
      }
    }
    if (t > 0) {    // L1 update(t-1): writes h1(t-1) -> A1H, captures encoded
      f32x4 accd = (f32x4){bd1r, bd1r, bd1r, bd1r};
#pragma unroll
      for (int kk = 0; kk < 4; ++kk) {
        bf16x8 a = *(const bf16x8*)&AT1[c16][kk * 32 + q8];
        accd = mfma16(a, bwd1[kk], accd);
      }
      const int tm1 = t - 1;
#pragma unroll
      for (int r = 0; r < 4; ++r) {
        float hs    = tanhfast(accd[r]);
        float dgate = sigmf(__fmaf_rn(dpre[r], wt1r, bt1r));
        float hstar = __fmaf_rn(hs, dgate - 1.f, htl1[r]);
        float cn    = tanhfast(__fmaf_rn(otl1[r], c1r[r], hstar));
        float hn    = otl1[r] * tanhfast(cn);
        float m     = mpre[r];
        float hl    = __fmaf_rn(m, hn - h1r[r], h1r[r]);
        float cl    = __fmaf_rn(m, cn - c1r[r], c1r[r]);
        h1r[r] = hl; c1r[r] = cl;
        A1H[q * 4 + r][nc] = (__bf16)hl;
        if (tm1 == lrow[r]) encr[r] = hl * m;
      }
    }
    // stage t+1 into slot pn (old pn data last read at I1-snapshot, behind B1)
    if (tid < 256 && t < 63) {
      AH[pn][srow][scol] = (__bf16)hv;
      if (scol == 5)
        dmL[pn][0][srow] = __fdividef(1.f, __logf(2.7182818284590452f + fmaxf(hv, 0.f)));
      if (scol == 0) dmL[pn][1][srow] = mv;
      if (t < 62) { hv = histrow[(t + 2) * 16]; mv = hmrow[t + 2]; }
    }
    __syncthreads();   // B2
  }

  // ---- decoder head: state = [hist[b,last,:16] | enc128]; LN; FC-ReLU-FC ----
  if (tid < 256)
    stateL[srow][scol] = hist[((long)(b0 + srow) * 64 + lastL[srow]) * 16 + scol];
#pragma unroll
  for (int r = 0; r < 4; ++r)
    stateL[q * 4 + r][16 + nc] = encr[r];
  __syncthreads();

  if (tid < 256) {
    float sm = 0.f, sq = 0.f;
    for (int k = scol; k < 144; k += 16) {
      float v = stateL[srow][k];
      sm += v; sq += v * v;
    }
    redS[srow][scol] = sm; redQ[srow][scol] = sq;
  }
  __syncthreads();
  if (tid < 16) {
    float sm = 0.f, sq = 0.f;
    for (int s2 = 0; s2 < 16; ++s2) { sm += redS[tid][s2]; sq += redQ[tid][s2]; }
    float mu  = sm * (1.f / 144.f);
    float var = sq * (1.f / 144.f) - mu * mu;
    redS[0][tid] = mu;
    redQ[0][tid] = rsqrtf(var + 1e-5f);
  }
  __syncthreads();
  if (tid < 256) {
    float mu = redS[0][srow], rs = redQ[0][srow];
    for (int k = scol; k < 144; k += 16)
      stateL[srow][k] = (stateL[srow][k] - mu) * rs * lng[k] + lnb[k];
  }
  __syncthreads();
  if (tid < 256) {
    float accw[8];
#pragma unroll
    for (int o = 0; o < 8; ++o) accw[o] = b1[scol + 16 * o];
    for (int k = 0; k < 144; ++k) {
      float sv = stateL[srow][k];
      const float* w = W1 + k * 128 + scol;
#pragma unroll
      for (int o = 0; o < 8; ++o) accw[o] += sv * w[16 * o];
    }
#pragma unroll
    for (int o = 0; o < 8; ++o) a1L[srow][scol + 16 * o] = fmaxf(accw[o], 0.f);
  }
  __syncthreads();
  for (int e = tid; e < 960; e += 512) {
    int row = e / 60, j = e - row * 60;
    float accv = b2[j];
    for (int k = 0; k < 128; ++k) accv += a1L[row][k] * W2[k * 60 + j];
    accv = (accv != accv) ? 0.f : fminf(fmaxf(accv, -1e4f), 1e4f);  // nan_to_num
    out[(b0 + row) * 60 + j] = accv;
  }
}

extern "C" void kernel_launch(void* const* d_in, const int* in_sizes, int n_in,
                              void* d_out, int out_size, void* d_ws, size_t ws_size,
                              hipStream_t stream) {
  const float* hist  = (const float*)d_in[0];
  const float* hmask = (const float*)d_in[1];
  const float* Wp    = (const float*)d_in[2];
  const float* bp    = (const float*)d_in[3];
  const float* Wx    = (const float*)d_in[4];
  const float* bx    = (const float*)d_in[5];
  const float* Uh    = (const float*)d_in[6];
  const float* Wd    = (const float*)d_in[7];
  const float* bd    = (const float*)d_in[8];
  const float* Wt    = (const float*)d_in[9];
  const float* bt    = (const float*)d_in[10];
  const float* lng   = (const float*)d_in[11];
  const float* lnb   = (const float*)d_in[12];
  const float* W1    = (const float*)d_in[13];
  const float* b1    = (const float*)d_in[14];
  const float* W2    = (const float*)d_in[15];
  const float* b2    = (const float*)d_in[16];
  float* out = (float*)d_out;

  char* ws = (char*)d_ws;
  __bf16* BT0  = (__bf16*)ws;
  __bf16* BWd0 = (__bf16*)(ws + OFF_BWD0);
  __bf16* BT1  = (__bf16*)(ws + OFF_BT1);
  __bf16* BWd1 = (__bf16*)(ws + OFF_BWD1);
  float*  bz0  = (float*)(ws + OFF_BZ0);

  hipFuncSetAttribute((const void*)tlstm_main,
                      hipFuncAttributeMaxDynamicSharedMemorySize, S_TOTAL);

  tlstm_fold<<<26, 256, 0, stream>>>(Wp, bp, Wx, bx, BT0, bz0);
  tlstm_pack<<<704, 256, 0, stream>>>(Wx, Uh, Wd, BT0, BWd0, BT1, BWd1);
  tlstm_main<<<256, 512, S_TOTAL, stream>>>(hist, hmask, BT0, BWd0, BT1, BWd1,
                                            bz0, bx, bd, Wt, bt, lng, lnb,
                                            W1, b1, W2, b2, out);
}

// Round 9
// 310.669 us; speedup vs baseline: 1.6187x; 1.0182x over previous
//
#include <hip/hip_runtime.h>
#include <hip/hip_bf16.h>

// TLSTM forecaster. R9 = R8's 2-barrier lagged pipeline with:
//  - zero-spill state: 3-slot dmL ring (no cross-barrier d/m snapshot)
//  - exp2-prescaled weights/biases: sigm/tanh = rcp(1+exp2(acc)) directly
//  - WB0 in fragment-order LDS ([wave][gate][kk][lane*16B]) -> conflict-free
//  - h0 A-frags read once, shared by L0-gates(t) and L1-gates(t-1)
// B=4096, L=64, D=16, H=128, NL=2, FUT*MD=60, HEAD_IN=144.
// grid=256 x 512 thr; block owns 16 batch rows; wave owns 16 N-cols.
// Gate order [i, o, c] (reference's f-gate is dead code).
// Scales: i,o,Wt: -log2(e); c,Wd: +2*log2(e)  (folded into packed weights)

typedef __bf16 bf16x8 __attribute__((ext_vector_type(8)));
typedef float  f32x4  __attribute__((ext_vector_type(4)));

__device__ __forceinline__ f32x4 mfma16(bf16x8 a, bf16x8 b, f32x4 c) {
  return __builtin_amdgcn_mfma_f32_16x16x32_bf16(a, b, c, 0, 0, 0);
}

#if __has_builtin(__builtin_amdgcn_exp2f)
__device__ __forceinline__ float fexp2(float x) { return __builtin_amdgcn_exp2f(x); }
#else
__device__ __forceinline__ float fexp2(float x) { return exp2f(x); }
#endif
#if __has_builtin(__builtin_amdgcn_rcpf)
__device__ __forceinline__ float frcp(float x) { return __builtin_amdgcn_rcpf(x); }
#else
__device__ __forceinline__ float frcp(float x) { return __fdividef(1.f, x); }
#endif
// prescaled: u = -1.4427*z  ->  sigm(z)
__device__ __forceinline__ float sigmE(float u) { return frcp(1.f + fexp2(u)); }
// prescaled: u = +2.8854*z  ->  tanh(z)
__device__ __forceinline__ float tanhE(float u) {
  return __fmaf_rn(-2.f, frcp(1.f + fexp2(u)), 1.f);
}
#define SCL_S (-1.44269504f)
#define SCL_T (2.88539008f)

// ---------------- ws layout (bytes) ----------------
// BT0f : frag-order L0 gate weights, 61440 bf16 = 122880 B @ 0
//        elem (n=g*128+w*16+c, k=kk*32+q*8+j) at ((w*3+g)*5+kk)*512+(q*16+c)*8+j
// BWd0 : [128][128] bf16 @ 122880   (x SCL_T)
// BT1  : [384][256] bf16 @ 155648   (k0..127 Wx1, 128..255 Uh1; x gate scale)
// BWd1 : [128][128] bf16 @ 352256   (x SCL_T)
// bz0  : [384] f32       @ 385024   (x gate scale)
#define OFF_BWD0 122880
#define OFF_BT1  155648
#define OFF_BWD1 352256
#define OFF_BZ0  385024

// ---------------- dynamic LDS layout (bytes) ----------------
#define S_WB0   0        // frag-order, 122880
#define S_AH    122880   // [2][16][40] bf16 = 2560 (cols 16..31 zero)
#define S_A0H   125440   // [16][136] bf16 = 4352 (h0)
#define S_A1H   129792   // [16][136] bf16 = 4352 (h1)
#define S_AT0   134144   // [16][136] bf16 = 4352
#define S_AT1   138496   // [16][136] bf16 = 4352
#define S_DM    142848   // [3][2][16] f32 = 384 (ring)
#define S_LAST  143232   // [16] int
#define S_TOTAL 143296
// head-stage aliases (over WB0):
#define S_STATE 0
#define S_A1L   9216
#define S_REDS  17408
#define S_REDQ  18432

__device__ __forceinline__ int bt0f_off(int n, int k) {
  int g = n >> 7, w = (n >> 4) & 7, c = n & 15;
  int kk = k >> 5, q = (k >> 3) & 3, j = k & 7;
  return ((w * 3 + g) * 5 + kk) * 512 + (q * 16 + c) * 8 + j;
}

__global__ void tlstm_fold(const float* __restrict__ Wp, const float* __restrict__ bp,
                           const float* __restrict__ Wx, const float* __restrict__ bx,
                           __bf16* __restrict__ BT0f, float* __restrict__ bz0) {
  int idx = blockIdx.x * 256 + threadIdx.x;
  if (idx >= 384 * 17) return;
  int n = idx / 17, kk = idx % 17;
  int npr = n & 127, g = n >> 7, gs = g + 1;               // src gates 1,2,3 = i,o,c
  float sg = (g == 2) ? SCL_T : SCL_S;
  const float* wxcol = Wx + (gs * 128) * 128 + npr;        // Wx[0][gs][h][npr]
  if (kk < 16) {
    const float* wprow = Wp + kk * 128;
    float s = 0.f;
    for (int h = 0; h < 128; ++h) s += wprow[h] * wxcol[h * 128];
    BT0f[bt0f_off(n, kk)] = (__bf16)(s * sg);
  } else {
    float s = bx[gs * 128 + npr];
    for (int h = 0; h < 128; ++h) s += bp[h] * wxcol[h * 128];
    bz0[n] = s * sg;
    for (int k2 = 16; k2 < 32; ++k2) BT0f[bt0f_off(n, k2)] = (__bf16)0.f;  // K-pad
  }
}

__global__ void tlstm_pack(const float* __restrict__ Wx, const float* __restrict__ Uh,
                           const float* __restrict__ Wd,
                           __bf16* __restrict__ BT0f, __bf16* __restrict__ BWd0,
                           __bf16* __restrict__ BT1, __bf16* __restrict__ BWd1) {
  int e = blockIdx.x * 256 + threadIdx.x;
  if (e < 49152) {                                  // BT0 Uh0 region (k' = k+32)
    int n = e >> 7, k = e & 127, npr = n & 127, g = n >> 7, gs = g + 1;
    float sg = (g == 2) ? SCL_T : SCL_S;
    BT0f[bt0f_off(n, k + 32)] = (__bf16)(Uh[(gs * 128 + k) * 128 + npr] * sg);
  } else if (e < 65536) {                           // BWd0 (x SCL_T)
    int e2 = e - 49152; int n = e2 >> 7, k = e2 & 127;
    BWd0[n * 128 + k] = (__bf16)(Wd[k * 128 + n] * SCL_T);
  } else if (e < 163840) {                          // BT1 = [Wx1 ; Uh1] (x gate scale)
    int e2 = e - 65536; int n = e2 >> 8, k = e2 & 255;
    int npr = n & 127, g = n >> 7, gs = g + 1;
    float sg = (g == 2) ? SCL_T : SCL_S;
    float v = (k < 128) ? Wx[((4 + gs) * 128 + k) * 128 + npr]
                        : Uh[((4 + gs) * 128 + (k - 128)) * 128 + npr];
    BT1[n * 256 + k] = (__bf16)(v * sg);
  } else if (e < 180224) {                          // BWd1 (x SCL_T)
    int e2 = e - 163840; int n = e2 >> 7, k = e2 & 127;
    BWd1[n * 128 + k] = (__bf16)(Wd[(128 + k) * 128 + n] * SCL_T);
  }
}

__global__ __launch_bounds__(512, 1) void tlstm_main(
    const float* __restrict__ hist, const float* __restrict__ hmask,
    const __bf16* __restrict__ BT0f, const __bf16* __restrict__ BWd0,
    const __bf16* __restrict__ BT1, const __bf16* __restrict__ BWd1,
    const float* __restrict__ bz0, const float* __restrict__ bx,
    const float* __restrict__ bd, const float* __restrict__ Wt,
    const float* __restrict__ bt, const float* __restrict__ lng,
    const float* __restrict__ lnb, const float* __restrict__ W1,
    const float* __restrict__ b1, const float* __restrict__ W2,
    const float* __restrict__ b2, float* __restrict__ out) {
  extern __shared__ __align__(16) char smem[];
  __bf16* WB0 = (__bf16*)(smem + S_WB0);
  __bf16 (*AH)[16][40]  = (__bf16(*)[16][40])(smem + S_AH);
  __bf16 (*A0H)[136]    = (__bf16(*)[136])(smem + S_A0H);
  __bf16 (*A1H)[136]    = (__bf16(*)[136])(smem + S_A1H);
  __bf16 (*AT0)[136]    = (__bf16(*)[136])(smem + S_AT0);
  __bf16 (*AT1)[136]    = (__bf16(*)[136])(smem + S_AT1);
  float (*dmL)[2][16]   = (float(*)[2][16])(smem + S_DM);   // [3 slots][d/m][row]
  int*   lastL          = (int*)(smem + S_LAST);
  float (*stateL)[144]  = (float(*)[144])(smem + S_STATE);
  float (*a1L)[128]     = (float(*)[128])(smem + S_A1L);
  float (*redS)[16]     = (float(*)[16])(smem + S_REDS);
  float (*redQ)[16]     = (float(*)[16])(smem + S_REDQ);

  const int tid  = threadIdx.x;
  const int wave = tid >> 6;
  const int lane = tid & 63;
  const int q    = lane >> 4;
  const int c16  = lane & 15;
  const int q8   = q * 8;
  const int b0   = blockIdx.x * 16;
  const int nc   = wave * 16 + c16;  // owned N-column (0..127)

  // ---- one-time init ----
  for (int i = tid * 8; i < 61440; i += 4096)          // BT0f -> LDS (linear copy)
    *(bf16x8*)(WB0 + i) = *(const bf16x8*)(BT0f + i);
  {
    __bf16* z = (__bf16*)(smem + S_AH);                // zero AH+A0H+A1H
    for (int i = tid; i < 5632; i += 512) z[i] = (__bf16)0.f;
  }
  if (tid < 16) {
    float s = 0.f;
    for (int t = 0; t < 64; ++t) s += hmask[(b0 + tid) * 64 + t];
    s = fminf(fmaxf(s, 1.f), 64.f);
    lastL[tid] = (int)s - 1;
  }

  // per-wave constants (biases prescaled)
  float bz0r[3], bz1r[3];
#pragma unroll
  for (int g = 0; g < 3; ++g) {
    float sg = (g == 2) ? SCL_T : SCL_S;
    bz0r[g] = bz0[g * 128 + nc];                 // already scaled in fold
    bz1r[g] = bx[(5 + g) * 128 + nc] * sg;
  }
  const float bd0r = bd[nc] * SCL_T,       bd1r = bd[128 + nc] * SCL_T;
  const float wt0r = Wt[nc] * SCL_S,       wt1r = Wt[128 + nc] * SCL_S;
  const float bt0r = bt[nc] * SCL_S,       bt1r = bt[128 + nc] * SCL_S;

  // frag-order WB0 bases: frag(g,kk) at ((wave*3+g)*5+kk)*512 + lane*8
  int offW[3];
#pragma unroll
  for (int g = 0; g < 3; ++g) offW[g] = ((wave * 3 + g) * 5) * 512 + lane * 8;

  // register weights: wf1 (24) + bwd0/1 (8) = 32 frags (proven no-spill)
  bf16x8 wf1[24], bwd0[4], bwd1[4];
#pragma unroll
  for (int g = 0; g < 3; ++g)
#pragma unroll
    for (int kk = 0; kk < 8; ++kk)
      wf1[g * 8 + kk] = *(const bf16x8*)(BT1 + (g * 128 + nc) * 256 + kk * 32 + q8);
#pragma unroll
  for (int kk = 0; kk < 4; ++kk) {
    bwd0[kk] = *(const bf16x8*)(BWd0 + nc * 128 + q8 + kk * 32);
    bwd1[kk] = *(const bf16x8*)(BWd1 + nc * 128 + q8 + kk * 32);
  }

  float h0r[4] = {}, c0r[4] = {}, h1r[4] = {}, c1r[4] = {}, encr[4] = {};

  __syncthreads();   // init complete

  int lrow[4];
#pragma unroll
  for (int r = 0; r < 4; ++r) lrow[r] = lastL[q * 4 + r];

  const int srow = (tid >> 4) & 15, scol = tid & 15;   // staging/head map (tid<256)
  const float* histrow = hist + (long)(b0 + srow) * 1024 + scol;
  const float* hmrow   = hmask + (long)(b0 + srow) * 64;

  // stage t=0 into dm slot 0 / AH slot 0; prefetch t=1
  float hv = 0.f, mv = 0.f;
  if (tid < 256) {
    float v0 = histrow[0];
    AH[0][srow][scol] = (__bf16)v0;
    if (scol == 5)
      dmL[0][0][srow] = __fdividef(1.f, __logf(2.7182818284590452f + fmaxf(v0, 0.f)));
    if (scol == 0) dmL[0][1][srow] = hmrow[0];
    hv = histrow[16];
    mv = hmrow[1];
  }
  __syncthreads();

  // lagged pipeline: iter t runs L0(t) and L1(t-1); t=64 drains L1(63).
  for (int t = 0; t <= 64; ++t) {
    const int p = t & 1, pn = p ^ 1;
    const int sp = t % 3, sm = (t + 2) % 3, sn = (t + 1) % 3;

    // ================= I1: gate GEMMs =================
    // shared A-frags: h0(t-1) used by BOTH GEMMs; h1(t-2); hist(t)
    bf16x8 a0h[4], a1h[4], ahf;
#pragma unroll
    for (int kk = 0; kk < 4; ++kk) {
      a0h[kk] = *(const bf16x8*)&A0H[c16][kk * 32 + q8];
      a1h[kk] = *(const bf16x8*)&A1H[c16][kk * 32 + q8];
    }
    ahf = *(const bf16x8*)&AH[p][c16][q8];

    float htl0[4], otl0[4], htl1[4], otl1[4];
    if (t > 0) {    // L1 gates(t-1): z = [h0(t-1)|h1(t-2)] @ wf1 (K=256, regs)
      f32x4 acc[3];
#pragma unroll
      for (int g = 0; g < 3; ++g) acc[g] = (f32x4){bz1r[g], bz1r[g], bz1r[g], bz1r[g]};
#pragma unroll
      for (int kk = 0; kk < 4; ++kk)
#pragma unroll
        for (int g = 0; g < 3; ++g) acc[g] = mfma16(a0h[kk], wf1[g * 8 + kk], acc[g]);
#pragma unroll
      for (int kk = 0; kk < 4; ++kk)
#pragma unroll
        for (int g = 0; g < 3; ++g) acc[g] = mfma16(a1h[kk], wf1[g * 8 + 4 + kk], acc[g]);
#pragma unroll
      for (int r = 0; r < 4; ++r) {
        float ht = tanhE(acc[2][r]) + sigmE(acc[0][r]);
        htl1[r] = ht;
        otl1[r] = sigmE(acc[1][r]);
        AT1[q * 4 + r][nc] = (__bf16)ht;
      }
    }
    if (t < 64) {   // L0 gates(t): z = [hist|0|h0(t-1)] @ WB0f (K=160, LDS frag-order)
      f32x4 acc[3];
#pragma unroll
      for (int g = 0; g < 3; ++g) acc[g] = (f32x4){bz0r[g], bz0r[g], bz0r[g], bz0r[g]};
#pragma unroll
      for (int g = 0; g < 3; ++g)
        acc[g] = mfma16(ahf, *(const bf16x8*)(WB0 + offW[g]), acc[g]);
#pragma unroll
      for (int kk = 0; kk < 4; ++kk)
#pragma unroll
        for (int g = 0; g < 3; ++g)
          acc[g] = mfma16(a0h[kk], *(const bf16x8*)(WB0 + offW[g] + (kk + 1) * 512), acc[g]);
#pragma unroll
      for (int r = 0; r < 4; ++r) {
        float ht = tanhE(acc[2][r]) + sigmE(acc[0][r]);
        htl0[r] = ht;
        otl0[r] = sigmE(acc[1][r]);
        AT0[q * 4 + r][nc] = (__bf16)ht;
      }
    }
    __syncthreads();   // B1

    // ================= I2: Wd GEMMs + state updates =================
    if (t < 64) {   // L0 update(t) -> h0(t) into A0H
      float drow[4], mrow[4];
#pragma unroll
      for (int r = 0; r < 4; ++r) {
        drow[r] = dmL[sp][0][q * 4 + r];
        mrow[r] = dmL[sp][1][q * 4 + r];
      }
      f32x4 accd = (f32x4){bd0r, bd0r, bd0r, bd0r};
#pragma unroll
      for (int kk = 0; kk < 4; ++kk) {
        bf16x8 a = *(const bf16x8*)&AT0[c16][kk * 32 + q8];
        accd = mfma16(a, bwd0[kk], accd);
      }
#pragma unroll
      for (int r = 0; r < 4; ++r) {
        float hs    = tanhE(accd[r]);
        float dgate = sigmE(__fmaf_rn(drow[r], wt0r, bt0r));
        float hstar = __fmaf_rn(hs, dgate - 1.f, htl0[r]);
        float cn    = tanhE(SCL_T * __fmaf_rn(otl0[r], c0r[r], hstar));
        float hn    = otl0[r] * tanhE(SCL_T * cn);
        float m     = mrow[r];
        float hl    = __fmaf_rn(m, hn - h0r[r], h0r[r]);
        float cl    = __fmaf_rn(m, cn - c0r[r], c0r[r]);
        h0r[r] = hl; c0r[r] = cl;
        A0H[q * 4 + r][nc] = (__bf16)hl;
      }
    }
    if (t > 0) {    // L1 update(t-1) -> h1(t-1) into A1H; capture encoded
      float dpre[4], mpre[4];
#pragma unroll
      for (int r = 0; r < 4; ++r) {
        dpre[r] = dmL[sm][0][q * 4 + r];
        mpre[r] = dmL[sm][1][q * 4 + r];
      }
      f32x4 accd = (f32x4){bd1r, bd1r, bd1r, bd1r};
#pragma unroll
      for (int kk = 0; kk < 4; ++kk) {
        bf16x8 a = *(const bf16x8*)&AT1[c16][kk * 32 + q8];
        accd = mfma16(a, bwd1[kk], accd);
      }
      const int tm1 = t - 1;
#pragma unroll
      for (int r = 0; r < 4; ++r) {
        float hs    = tanhE(accd[r]);
        float dgate = sigmE(__fmaf_rn(dpre[r], wt1r, bt1r));
        float hstar = __fmaf_rn(hs, dgate - 1.f, htl1[r]);
        float cn    = tanhE(SCL_T * __fmaf_rn(otl1[r], c1r[r], hstar));
        float hn    = otl1[r] * tanhE(SCL_T * cn);
        float m     = mpre[r];
        float hl    = __fmaf_rn(m, hn - h1r[r], h1r[r]);
        float cl    = __fmaf_rn(m, cn - c1r[r], c1r[r]);
        h1r[r] = hl; c1r[r] = cl;
        A1H[q * 4 + r][nc] = (__bf16)hl;
        if (tm1 == lrow[r]) encr[r] = hl * m;
      }
    }
    // stage t+1 into AH[pn] / dm slot sn (distinct from sp, sm)
    if (tid < 256 && t < 63) {
      AH[pn][srow][scol] = (__bf16)hv;
      if (scol == 5)
        dmL[sn][0][srow] = __fdividef(1.f, __logf(2.7182818284590452f + fmaxf(hv, 0.f)));
      if (scol == 0) dmL[sn][1][srow] = mv;
      if (t < 62) { hv = histrow[(t + 2) * 16]; mv = hmrow[t + 2]; }
    }
    __syncthreads();   // B2
  }

  // ---- decoder head: state = [hist[b,last,:16] | enc128]; LN; FC-ReLU-FC ----
  if (tid < 256)
    stateL[srow][scol] = hist[((long)(b0 + srow) * 64 + lastL[srow]) * 16 + scol];
#pragma unroll
  for (int r = 0; r < 4; ++r)
    stateL[q * 4 + r][16 + nc] = encr[r];
  __syncthreads();

  if (tid < 256) {
    float sm2 = 0.f, sq = 0.f;
    for (int k = scol; k < 144; k += 16) {
      float v = stateL[srow][k];
      sm2 += v; sq += v * v;
    }
    redS[srow][scol] = sm2; redQ[srow][scol] = sq;
  }
  __syncthreads();
  if (tid < 16) {
    float sm2 = 0.f, sq = 0.f;
    for (int s2 = 0; s2 < 16; ++s2) { sm2 += redS[tid][s2]; sq += redQ[tid][s2]; }
    float mu  = sm2 * (1.f / 144.f);
    float var = sq * (1.f / 144.f) - mu * mu;
    redS[0][tid] = mu;
    redQ[0][tid] = rsqrtf(var + 1e-5f);
  }
  __syncthreads();
  if (tid < 256) {
    float mu = redS[0][srow], rs = redQ[0][srow];
    for (int k = scol; k < 144; k += 16)
      stateL[srow][k] = (stateL[srow][k] - mu) * rs * lng[k] + lnb[k];
  }
  __syncthreads();
  if (tid < 256) {
    float accw[8];
#pragma unroll
    for (int o = 0; o < 8; ++o) accw[o] = b1[scol + 16 * o];
    for (int k = 0; k < 144; ++k) {
      float sv = stateL[srow][k];
      const float* w = W1 + k * 128 + scol;
#pragma unroll
      for (int o = 0; o < 8; ++o) accw[o] += sv * w[16 * o];
    }
#pragma unroll
    for (int o = 0; o < 8; ++o) a1L[srow][scol + 16 * o] = fmaxf(accw[o], 0.f);
  }
  __syncthreads();
  for (int e = tid; e < 960; e += 512) {
    int row = e / 60, j = e - row * 60;
    float accv = b2[j];
    for (int k = 0; k < 128; ++k) accv += a1L[row][k] * W2[k * 60 + j];
    accv = (accv != accv) ? 0.f : fminf(fmaxf(accv, -1e4f), 1e4f);  // nan_to_num
    out[(b0 + row) * 60 + j] = accv;
  }
}

extern "C" void kernel_launch(void* const* d_in, const int* in_sizes, int n_in,
                              void* d_out, int out_size, void* d_ws, size_t ws_size,
                              hipStream_t stream) {
  const float* hist  = (const float*)d_in[0];
  const float* hmask = (const float*)d_in[1];
  const float* Wp    = (const float*)d_in[2];
  const float* bp    = (const float*)d_in[3];
  const float* Wx    = (const float*)d_in[4];
  const float* bx    = (const float*)d_in[5];
  const float* Uh    = (const float*)d_in[6];
  const float* Wd    = (const float*)d_in[7];
  const float* bd    = (const float*)d_in[8];
  const float* Wt    = (const float*)d_in[9];
  const float* bt    = (const float*)d_in[10];
  const float* lng   = (const float*)d_in[11];
  const float* lnb   = (const float*)d_in[12];
  const float* W1    = (const float*)d_in[13];
  const float* b1    = (const float*)d_in[14];
  const float* W2    = (const float*)d_in[15];
  const float* b2    = (const float*)d_in[16];
  float* out = (float*)d_out;

  char* ws = (char*)d_ws;
  __bf16* BT0f = (__bf16*)ws;
  __bf16* BWd0 = (__bf16*)(ws + OFF_BWD0);
  __bf16* BT1  = (__bf16*)(ws + OFF_BT1);
  __bf16* BWd1 = (__bf16*)(ws + OFF_BWD1);
  float*  bz0  = (float*)(ws + OFF_BZ0);

  hipFuncSetAttribute((const void*)tlstm_main,
                      hipFuncAttributeMaxDynamicSharedMemorySize, S_TOTAL);

  tlstm_fold<<<26, 256, 0, stream>>>(Wp, bp, Wx, bx, BT0f, bz0);
  tlstm_pack<<<704, 256, 0, stream>>>(Wx, Uh, Wd, BT0f, BWd0, BT1, BWd1);
  tlstm_main<<<256, 512, S_TOTAL, stream>>>(hist, hmask, BT0f, BWd0, BT1, BWd1,
                                            bz0, bx, bd, Wt, bt, lng, lnb,
                                            W1, b1, W2, b2, out);
}

// Round 10
// 301.733 us; speedup vs baseline: 1.6667x; 1.0296x over previous
//
#include <hip/hip_runtime.h>
#include <hip/hip_bf16.h>

// TLSTM forecaster. R10 = R9 main kernel (unchanged) + merged coalesced
// prologue: fold+pack in ONE kernel, n-fastest mapping so every global read
// is coalesced (prologue was 79us = 25% of wall in R9).
// B=4096, L=64, D=16, H=128, NL=2, FUT*MD=60, HEAD_IN=144.
// grid=256 x 512 thr; block owns 16 batch rows; wave owns 16 N-cols.
// Gate order [i, o, c] (reference's f-gate is dead code).
// Scales: i,o,Wt: -log2(e); c,Wd: +2*log2(e)  (folded into packed weights)

typedef __bf16 bf16x8 __attribute__((ext_vector_type(8)));
typedef float  f32x4  __attribute__((ext_vector_type(4)));

__device__ __forceinline__ f32x4 mfma16(bf16x8 a, bf16x8 b, f32x4 c) {
  return __builtin_amdgcn_mfma_f32_16x16x32_bf16(a, b, c, 0, 0, 0);
}

#if __has_builtin(__builtin_amdgcn_exp2f)
__device__ __forceinline__ float fexp2(float x) { return __builtin_amdgcn_exp2f(x); }
#else
__device__ __forceinline__ float fexp2(float x) { return exp2f(x); }
#endif
#if __has_builtin(__builtin_amdgcn_rcpf)
__device__ __forceinline__ float frcp(float x) { return __builtin_amdgcn_rcpf(x); }
#else
__device__ __forceinline__ float frcp(float x) { return __fdividef(1.f, x); }
#endif
// prescaled: u = -1.4427*z  ->  sigm(z)
__device__ __forceinline__ float sigmE(float u) { return frcp(1.f + fexp2(u)); }
// prescaled: u = +2.8854*z  ->  tanh(z)
__device__ __forceinline__ float tanhE(float u) {
  return __fmaf_rn(-2.f, frcp(1.f + fexp2(u)), 1.f);
}
#define SCL_S (-1.44269504f)
#define SCL_T (2.88539008f)

// ---------------- ws layout (bytes) ----------------
// BT0f : frag-order L0 gate weights, 61440 bf16 = 122880 B @ 0
//        elem (n=g*128+w*16+c, k=kk*32+q*8+j) at ((w*3+g)*5+kk)*512+(q*16+c)*8+j
// BWd0 : [128][128] bf16 @ 122880   (x SCL_T)
// BT1  : [384][256] bf16 @ 155648   (k0..127 Wx1, 128..255 Uh1; x gate scale)
// BWd1 : [128][128] bf16 @ 352256   (x SCL_T)
// bz0  : [384] f32       @ 385024   (x gate scale)
#define OFF_BWD0 122880
#define OFF_BT1  155648
#define OFF_BWD1 352256
#define OFF_BZ0  385024

// ---------------- dynamic LDS layout (bytes) ----------------
#define S_WB0   0        // frag-order, 122880
#define S_AH    122880   // [2][16][40] bf16 = 2560 (cols 16..31 zero)
#define S_A0H   125440   // [16][136] bf16 = 4352 (h0)
#define S_A1H   129792   // [16][136] bf16 = 4352 (h1)
#define S_AT0   134144   // [16][136] bf16 = 4352
#define S_AT1   138496   // [16][136] bf16 = 4352
#define S_DM    142848   // [3][2][16] f32 = 384 (ring)
#define S_LAST  143232   // [16] int
#define S_TOTAL 143296
// head-stage aliases (over WB0):
#define S_STATE 0
#define S_A1L   9216
#define S_REDS  17408
#define S_REDQ  18432

__device__ __forceinline__ int bt0f_off(int n, int k) {
  int g = n >> 7, w = (n >> 4) & 7, c = n & 15;
  int kk = k >> 5, q = (k >> 3) & 3, j = k & 7;
  return ((w * 3 + g) * 5 + kk) * 512 + (q * 16 + c) * 8 + j;
}

// Merged prologue, n-fastest mapping (coalesced reads everywhere).
// blocks 0..25: fold (Wp@Wx0 K=16 region + bias); blocks 26..729: pack.
__global__ void tlstm_prep(const float* __restrict__ Wp, const float* __restrict__ bp,
                           const float* __restrict__ Wx, const float* __restrict__ bx,
                           const float* __restrict__ Uh, const float* __restrict__ Wd,
                           __bf16* __restrict__ BT0f, __bf16* __restrict__ BWd0,
                           __bf16* __restrict__ BT1, __bf16* __restrict__ BWd1,
                           float* __restrict__ bz0) {
  if (blockIdx.x < 26) {
    int idx = blockIdx.x * 256 + threadIdx.x;          // (n fastest)
    if (idx >= 384 * 17) return;
    int kk = idx / 384, n = idx - kk * 384;
    int npr = n & 127, g = n >> 7, gs = g + 1;         // src gates 1,2,3 = i,o,c
    float sg = (g == 2) ? SCL_T : SCL_S;
    const float* wxg = Wx + (gs * 128) * 128 + npr;    // Wx[0][gs][h][npr]
    if (kk < 16) {
      const float* wprow = Wp + kk * 128;
      float s = 0.f;
      for (int h = 0; h < 128; ++h) s += wprow[h] * wxg[h * 128];   // lane-coalesced
      BT0f[bt0f_off(n, kk)] = (__bf16)(s * sg);
    } else {
      float s = bx[gs * 128 + npr];
      for (int h = 0; h < 128; ++h) s += bp[h] * wxg[h * 128];
      bz0[n] = s * sg;
      for (int k2 = 16; k2 < 32; ++k2) BT0f[bt0f_off(n, k2)] = (__bf16)0.f;  // K-pad
    }
    return;
  }
  int e = (blockIdx.x - 26) * 256 + threadIdx.x;
  if (e < 49152) {                                  // BT0f Uh0 (384n x 128k), n fastest
    int k = e / 384, n = e - k * 384;
    int npr = n & 127, g = n >> 7, gs = g + 1;
    float sg = (g == 2) ? SCL_T : SCL_S;
    BT0f[bt0f_off(n, k + 32)] = (__bf16)(Uh[(gs * 128 + k) * 128 + npr] * sg);
  } else if (e < 65536) {                           // BWd0 (128n x 128k), n fastest
    int e2 = e - 49152; int k = e2 >> 7, n = e2 & 127;
    BWd0[n * 128 + k] = (__bf16)(Wd[k * 128 + n] * SCL_T);
  } else if (e < 163840) {                          // BT1 (384n x 256k), n fastest
    int e2 = e - 65536; int k = e2 / 384, n = e2 - k * 384;
    int npr = n & 127, g = n >> 7, gs = g + 1;
    float sg = (g == 2) ? SCL_T : SCL_S;
    float v = (k < 128) ? Wx[((4 + gs) * 128 + k) * 128 + npr]
                        : Uh[((4 + gs) * 128 + (k - 128)) * 128 + npr];
    BT1[n * 256 + k] = (__bf16)(v * sg);
  } else if (e < 180224) {                          // BWd1 (128n x 128k), n fastest
    int e2 = e - 163840; int k = e2 >> 7, n = e2 & 127;
    BWd1[n * 128 + k] = (__bf16)(Wd[(128 + k) * 128 + n] * SCL_T);
  }
}

__global__ __launch_bounds__(512, 1) void tlstm_main(
    const float* __restrict__ hist, const float* __restrict__ hmask,
    const __bf16* __restrict__ BT0f, const __bf16* __restrict__ BWd0,
    const __bf16* __restrict__ BT1, const __bf16* __restrict__ BWd1,
    const float* __restrict__ bz0, const float* __restrict__ bx,
    const float* __restrict__ bd, const float* __restrict__ Wt,
    const float* __restrict__ bt, const float* __restrict__ lng,
    const float* __restrict__ lnb, const float* __restrict__ W1,
    const float* __restrict__ b1, const float* __restrict__ W2,
    const float* __restrict__ b2, float* __restrict__ out) {
  extern __shared__ __align__(16) char smem[];
  __bf16* WB0 = (__bf16*)(smem + S_WB0);
  __bf16 (*AH)[16][40]  = (__bf16(*)[16][40])(smem + S_AH);
  __bf16 (*A0H)[136]    = (__bf16(*)[136])(smem + S_A0H);
  __bf16 (*A1H)[136]    = (__bf16(*)[136])(smem + S_A1H);
  __bf16 (*AT0)[136]    = (__bf16(*)[136])(smem + S_AT0);
  __bf16 (*AT1)[136]    = (__bf16(*)[136])(smem + S_AT1);
  float (*dmL)[2][16]   = (float(*)[2][16])(smem + S_DM);   // [3 slots][d/m][row]
  int*   lastL          = (int*)(smem + S_LAST);
  float (*stateL)[144]  = (float(*)[144])(smem + S_STATE);
  float (*a1L)[128]     = (float(*)[128])(smem + S_A1L);
  float (*redS)[16]     = (float(*)[16])(smem + S_REDS);
  float (*redQ)[16]     = (float(*)[16])(smem + S_REDQ);

  const int tid  = threadIdx.x;
  const int wave = tid >> 6;
  const int lane = tid & 63;
  const int q    = lane >> 4;
  const int c16  = lane & 15;
  const int q8   = q * 8;
  const int b0   = blockIdx.x * 16;
  const int nc   = wave * 16 + c16;  // owned N-column (0..127)

  // ---- one-time init ----
  for (int i = tid * 8; i < 61440; i += 4096)          // BT0f -> LDS (linear copy)
    *(bf16x8*)(WB0 + i) = *(const bf16x8*)(BT0f + i);
  {
    __bf16* z = (__bf16*)(smem + S_AH);                // zero AH+A0H+A1H
    for (int i = tid; i < 5632; i += 512) z[i] = (__bf16)0.f;
  }
  if (tid < 16) {
    float s = 0.f;
    for (int t = 0; t < 64; ++t) s += hmask[(b0 + tid) * 64 + t];
    s = fminf(fmaxf(s, 1.f), 64.f);
    lastL[tid] = (int)s - 1;
  }

  // per-wave constants (biases prescaled)
  float bz0r[3], bz1r[3];
#pragma unroll
  for (int g = 0; g < 3; ++g) {
    float sg = (g == 2) ? SCL_T : SCL_S;
    bz0r[g] = bz0[g * 128 + nc];                 // already scaled in prep
    bz1r[g] = bx[(5 + g) * 128 + nc] * sg;
  }
  const float bd0r = bd[nc] * SCL_T,       bd1r = bd[128 + nc] * SCL_T;
  const float wt0r = Wt[nc] * SCL_S,       wt1r = Wt[128 + nc] * SCL_S;
  const float bt0r = bt[nc] * SCL_S,       bt1r = bt[128 + nc] * SCL_S;

  // frag-order WB0 bases: frag(g,kk) at ((wave*3+g)*5+kk)*512 + lane*8
  int offW[3];
#pragma unroll
  for (int g = 0; g < 3; ++g) offW[g] = ((wave * 3 + g) * 5) * 512 + lane * 8;

  // register weights: wf1 (24) + bwd0/1 (8) = 32 frags (proven no-spill)
  bf16x8 wf1[24], bwd0[4], bwd1[4];
#pragma unroll
  for (int g = 0; g < 3; ++g)
#pragma unroll
    for (int kk = 0; kk < 8; ++kk)
      wf1[g * 8 + kk] = *(const bf16x8*)(BT1 + (g * 128 + nc) * 256 + kk * 32 + q8);
#pragma unroll
  for (int kk = 0; kk < 4; ++kk) {
    bwd0[kk] = *(const bf16x8*)(BWd0 + nc * 128 + q8 + kk * 32);
    bwd1[kk] = *(const bf16x8*)(BWd1 + nc * 128 + q8 + kk * 32);
  }

  float h0r[4] = {}, c0r[4] = {}, h1r[4] = {}, c1r[4] = {}, encr[4] = {};

  __syncthreads();   // init complete

  int lrow[4];
#pragma unroll
  for (int r = 0; r < 4; ++r) lrow[r] = lastL[q * 4 + r];

  const int srow = (tid >> 4) & 15, scol = tid & 15;   // staging/head map (tid<256)
  const float* histrow = hist + (long)(b0 + srow) * 1024 + scol;
  const float* hmrow   = hmask + (long)(b0 + srow) * 64;

  // stage t=0 into dm slot 0 / AH slot 0; prefetch t=1
  float hv = 0.f, mv = 0.f;
  if (tid < 256) {
    float v0 = histrow[0];
    AH[0][srow][scol] = (__bf16)v0;
    if (scol == 5)
      dmL[0][0][srow] = __fdividef(1.f, __logf(2.7182818284590452f + fmaxf(v0, 0.f)));
    if (scol == 0) dmL[0][1][srow] = hmrow[0];
    hv = histrow[16];
    mv = hmrow[1];
  }
  __syncthreads();

  // lagged pipeline: iter t runs L0(t) and L1(t-1); t=64 drains L1(63).
  for (int t = 0; t <= 64; ++t) {
    const int p = t & 1, pn = p ^ 1;
    const int sp = t % 3, sm = (t + 2) % 3, sn = (t + 1) % 3;

    // ================= I1: gate GEMMs =================
    // shared A-frags: h0(t-1) used by BOTH GEMMs; h1(t-2); hist(t)
    bf16x8 a0h[4], a1h[4], ahf;
#pragma unroll
    for (int kk = 0; kk < 4; ++kk) {
      a0h[kk] = *(const bf16x8*)&A0H[c16][kk * 32 + q8];
      a1h[kk] = *(const bf16x8*)&A1H[c16][kk * 32 + q8];
    }
    ahf = *(const bf16x8*)&AH[p][c16][q8];

    float htl0[4], otl0[4], htl1[4], otl1[4];
    if (t > 0) {    // L1 gates(t-1): z = [h0(t-1)|h1(t-2)] @ wf1 (K=256, regs)
      f32x4 acc[3];
#pragma unroll
      for (int g = 0; g < 3; ++g) acc[g] = (f32x4){bz1r[g], bz1r[g], bz1r[g], bz1r[g]};
#pragma unroll
      for (int kk = 0; kk < 4; ++kk)
#pragma unroll
        for (int g = 0; g < 3; ++g) acc[g] = mfma16(a0h[kk], wf1[g * 8 + kk], acc[g]);
#pragma unroll
      for (int kk = 0; kk < 4; ++kk)
#pragma unroll
        for (int g = 0; g < 3; ++g) acc[g] = mfma16(a1h[kk], wf1[g * 8 + 4 + kk], acc[g]);
#pragma unroll
      for (int r = 0; r < 4; ++r) {
        float ht = tanhE(acc[2][r]) + sigmE(acc[0][r]);
        htl1[r] = ht;
        otl1[r] = sigmE(acc[1][r]);
        AT1[q * 4 + r][nc] = (__bf16)ht;
      }
    }
    if (t < 64) {   // L0 gates(t): z = [hist|0|h0(t-1)] @ WB0f (K=160, LDS frag-order)
      f32x4 acc[3];
#pragma unroll
      for (int g = 0; g < 3; ++g) acc[g] = (f32x4){bz0r[g], bz0r[g], bz0r[g], bz0r[g]};
#pragma unroll
      for (int g = 0; g < 3; ++g)
        acc[g] = mfma16(ahf, *(const bf16x8*)(WB0 + offW[g]), acc[g]);
#pragma unroll
      for (int kk = 0; kk < 4; ++kk)
#pragma unroll
        for (int g = 0; g < 3; ++g)
          acc[g] = mfma16(a0h[kk], *(const bf16x8*)(WB0 + offW[g] + (kk + 1) * 512), acc[g]);
#pragma unroll
      for (int r = 0; r < 4; ++r) {
        float ht = tanhE(acc[2][r]) + sigmE(acc[0][r]);
        htl0[r] = ht;
        otl0[r] = sigmE(acc[1][r]);
        AT0[q * 4 + r][nc] = (__bf16)ht;
      }
    }
    __syncthreads();   // B1

    // ================= I2: Wd GEMMs + state updates =================
    if (t < 64) {   // L0 update(t) -> h0(t) into A0H
      float drow[4], mrow[4];
#pragma unroll
      for (int r = 0; r < 4; ++r) {
        drow[r] = dmL[sp][0][q * 4 + r];
        mrow[r] = dmL[sp][1][q * 4 + r];
      }
      f32x4 accd = (f32x4){bd0r, bd0r, bd0r, bd0r};
#pragma unroll
      for (int kk = 0; kk < 4; ++kk) {
        bf16x8 a = *(const bf16x8*)&AT0[c16][kk * 32 + q8];
        accd = mfma16(a, bwd0[kk], accd);
      }
#pragma unroll
      for (int r = 0; r < 4; ++r) {
        float hs    = tanhE(accd[r]);
        float dgate = sigmE(__fmaf_rn(drow[r], wt0r, bt0r));
        float hstar = __fmaf_rn(hs, dgate - 1.f, htl0[r]);
        float cn    = tanhE(SCL_T * __fmaf_rn(otl0[r], c0r[r], hstar));
        float hn    = otl0[r] * tanhE(SCL_T * cn);
        float m     = mrow[r];
        float hl    = __fmaf_rn(m, hn - h0r[r], h0r[r]);
        float cl    = __fmaf_rn(m, cn - c0r[r], c0r[r]);
        h0r[r] = hl; c0r[r] = cl;
        A0H[q * 4 + r][nc] = (__bf16)hl;
      }
    }
    if (t > 0) {    // L1 update(t-1) -> h1(t-1) into A1H; capture encoded
      float dpre[4], mpre[4];
#pragma unroll
      for (int r = 0; r < 4; ++r) {
        dpre[r] = dmL[sm][0][q * 4 + r];
        mpre[r] = dmL[sm][1][q * 4 + r];
      }
      f32x4 accd = (f32x4){bd1r, bd1r, bd1r, bd1r};
#pragma unroll
      for (int kk = 0; kk < 4; ++kk) {
        bf16x8 a = *(const bf16x8*)&AT1[c16][kk * 32 + q8];
        accd = mfma16(a, bwd1[kk], accd);
      }
      const int tm1 = t - 1;
#pragma unroll
      for (int r = 0; r < 4; ++r) {
        float hs    = tanhE(accd[r]);
        float dgate = sigmE(__fmaf_rn(dpre[r], wt1r, bt1r));
        float hstar = __fmaf_rn(hs, dgate - 1.f, htl1[r]);
        float cn    = tanhE(SCL_T * __fmaf_rn(otl1[r], c1r[r], hstar));
        float hn    = otl1[r] * tanhE(SCL_T * cn);
        float m     = mpre[r];
        float hl    = __fmaf_rn(m, hn - h1r[r], h1r[r]);
        float cl    = __fmaf_rn(m, cn - c1r[r], c1r[r]);
        h1r[r] = hl; c1r[r] = cl;
        A1H[q * 4 + r][nc] = (__bf16)hl;
        if (tm1 == lrow[r]) encr[r] = hl * m;
      }
    }
    // stage t+1 into AH[pn] / dm slot sn (distinct from sp, sm)
    if (tid < 256 && t < 63) {
      AH[pn][srow][scol] = (__bf16)hv;
      if (scol == 5)
        dmL[sn][0][srow] = __fdividef(1.f, __logf(2.7182818284590452f + fmaxf(hv, 0.f)));
      if (scol == 0) dmL[sn][1][srow] = mv;
      if (t < 62) { hv = histrow[(t + 2) * 16]; mv = hmrow[t + 2]; }
    }
    __syncthreads();   // B2
  }

  // ---- decoder head: state = [hist[b,last,:16] | enc128]; LN; FC-ReLU-FC ----
  if (tid < 256)
    stateL[srow][scol] = hist[((long)(b0 + srow) * 64 + lastL[srow]) * 16 + scol];
#pragma unroll
  for (int r = 0; r < 4; ++r)
    stateL[q * 4 + r][16 + nc] = encr[r];
  __syncthreads();

  if (tid < 256) {
    float sm2 = 0.f, sq = 0.f;
    for (int k = scol; k < 144; k += 16) {
      float v = stateL[srow][k];
      sm2 += v; sq += v * v;
    }
    redS[srow][scol] = sm2; redQ[srow][scol] = sq;
  }
  __syncthreads();
  if (tid < 16) {
    float sm2 = 0.f, sq = 0.f;
    for (int s2 = 0; s2 < 16; ++s2) { sm2 += redS[tid][s2]; sq += redQ[tid][s2]; }
    float mu  = sm2 * (1.f / 144.f);
    float var = sq * (1.f / 144.f) - mu * mu;
    redS[0][tid] = mu;
    redQ[0][tid] = rsqrtf(var + 1e-5f);
  }
  __syncthreads();
  if (tid < 256) {
    float mu = redS[0][srow], rs = redQ[0][srow];
    for (int k = scol; k < 144; k += 16)
      stateL[srow][k] = (stateL[srow][k] - mu) * rs * lng[k] + lnb[k];
  }
  __syncthreads();
  if (tid < 256) {
    float accw[8];
#pragma unroll
    for (int o = 0; o < 8; ++o) accw[o] = b1[scol + 16 * o];
    for (int k = 0; k < 144; ++k) {
      float sv = stateL[srow][k];
      const float* w = W1 + k * 128 + scol;
#pragma unroll
      for (int o = 0; o < 8; ++o) accw[o] += sv * w[16 * o];
    }
#pragma unroll
    for (int o = 0; o < 8; ++o) a1L[srow][scol + 16 * o] = fmaxf(accw[o], 0.f);
  }
  __syncthreads();
  for (int e = tid; e < 960; e += 512) {
    int row = e / 60, j = e - row * 60;
    float accv = b2[j];
    for (int k = 0; k < 128; ++k) accv += a1L[row][k] * W2[k * 60 + j];
    accv = (accv != accv) ? 0.f : fminf(fmaxf(accv, -1e4f), 1e4f);  // nan_to_num
    out[(b0 + row) * 60 + j] = accv;
  }
}

extern "C" void kernel_launch(void* const* d_in, const int* in_sizes, int n_in,
                              void* d_out, int out_size, void* d_ws, size_t ws_size,
                              hipStream_t stream) {
  const float* hist  = (const float*)d_in[0];
  const float* hmask = (const float*)d_in[1];
  const float* Wp    = (const float*)d_in[2];
  const float* bp    = (const float*)d_in[3];
  const float* Wx    = (const float*)d_in[4];
  const float* bx    = (const float*)d_in[5];
  const float* Uh    = (const float*)d_in[6];
  const float* Wd    = (const float*)d_in[7];
  const float* bd    = (const float*)d_in[8];
  const float* Wt    = (const float*)d_in[9];
  const float* bt    = (const float*)d_in[10];
  const float* lng   = (const float*)d_in[11];
  const float* lnb   = (const float*)d_in[12];
  const float* W1    = (const float*)d_in[13];
  const float* b1    = (const float*)d_in[14];
  const float* W2    = (const float*)d_in[15];
  const float* b2    = (const float*)d_in[16];
  float* out = (float*)d_out;

  char* ws = (char*)d_ws;
  __bf16* BT0f = (__bf16*)ws;
  __bf16* BWd0 = (__bf16*)(ws + OFF_BWD0);
  __bf16* BT1  = (__bf16*)(ws + OFF_BT1);
  __bf16* BWd1 = (__bf16*)(ws + OFF_BWD1);
  float*  bz0  = (float*)(ws + OFF_BZ0);

  hipFuncSetAttribute((const void*)tlstm_main,
                      hipFuncAttributeMaxDynamicSharedMemorySize, S_TOTAL);

  tlstm_prep<<<730, 256, 0, stream>>>(Wp, bp, Wx, bx, Uh, Wd,
                                      BT0f, BWd0, BT1, BWd1, bz0);
  tlstm_main<<<256, 512, S_TOTAL, stream>>>(hist, hmask, BT0f, BWd0, BT1, BWd1,
                                            bz0, bx, bd, Wt, bt, lng, lnb,
                                            W1, b1, W2, b2, out);
}

// Round 11
// 300.150 us; speedup vs baseline: 1.6755x; 1.0053x over previous
//
#include <hip/hip_runtime.h>
#include <hip/hip_bf16.h>

// TLSTM forecaster. R11 = R10 with spill-elimination in the pipelined loop:
//  - A-frags NOT shared across I1's two GEMMs (each section loads its own;
//    R9's sharing held 9 frags live across both chains -> ~5MB scratch spill)
//  - htl0/htl1 not carried in regs across B1: re-read from AT0/AT1 (bf16)
// Everything else identical to R10: frag-order WB0 in LDS, wf1+bwd in regs,
// exp2-prescaled trans, 3-slot dm ring, merged coalesced prologue.
// B=4096, L=64, D=16, H=128, NL=2, FUT*MD=60, HEAD_IN=144.
// grid=256 x 512 thr; block owns 16 batch rows; wave owns 16 N-cols.
// Gate order [i, o, c] (reference's f-gate is dead code).
// Scales: i,o,Wt: -log2(e); c,Wd: +2*log2(e)  (folded into packed weights)

typedef __bf16 bf16x8 __attribute__((ext_vector_type(8)));
typedef float  f32x4  __attribute__((ext_vector_type(4)));

__device__ __forceinline__ f32x4 mfma16(bf16x8 a, bf16x8 b, f32x4 c) {
  return __builtin_amdgcn_mfma_f32_16x16x32_bf16(a, b, c, 0, 0, 0);
}

#if __has_builtin(__builtin_amdgcn_exp2f)
__device__ __forceinline__ float fexp2(float x) { return __builtin_amdgcn_exp2f(x); }
#else
__device__ __forceinline__ float fexp2(float x) { return exp2f(x); }
#endif
#if __has_builtin(__builtin_amdgcn_rcpf)
__device__ __forceinline__ float frcp(float x) { return __builtin_amdgcn_rcpf(x); }
#else
__device__ __forceinline__ float frcp(float x) { return __fdividef(1.f, x); }
#endif
// prescaled: u = -1.4427*z  ->  sigm(z)
__device__ __forceinline__ float sigmE(float u) { return frcp(1.f + fexp2(u)); }
// prescaled: u = +2.8854*z  ->  tanh(z)
__device__ __forceinline__ float tanhE(float u) {
  return __fmaf_rn(-2.f, frcp(1.f + fexp2(u)), 1.f);
}
#define SCL_S (-1.44269504f)
#define SCL_T (2.88539008f)

// ---------------- ws layout (bytes) ----------------
// BT0f : frag-order L0 gate weights, 61440 bf16 = 122880 B @ 0
//        elem (n=g*128+w*16+c, k=kk*32+q*8+j) at ((w*3+g)*5+kk)*512+(q*16+c)*8+j
// BWd0 : [128][128] bf16 @ 122880   (x SCL_T)
// BT1  : [384][256] bf16 @ 155648   (k0..127 Wx1, 128..255 Uh1; x gate scale)
// BWd1 : [128][128] bf16 @ 352256   (x SCL_T)
// bz0  : [384] f32       @ 385024   (x gate scale)
#define OFF_BWD0 122880
#define OFF_BT1  155648
#define OFF_BWD1 352256
#define OFF_BZ0  385024

// ---------------- dynamic LDS layout (bytes) ----------------
#define S_WB0   0        // frag-order, 122880
#define S_AH    122880   // [2][16][40] bf16 = 2560 (cols 16..31 zero)
#define S_A0H   125440   // [16][136] bf16 = 4352 (h0)
#define S_A1H   129792   // [16][136] bf16 = 4352 (h1)
#define S_AT0   134144   // [16][136] bf16 = 4352
#define S_AT1   138496   // [16][136] bf16 = 4352
#define S_DM    142848   // [3][2][16] f32 = 384 (ring)
#define S_LAST  143232   // [16] int
#define S_TOTAL 143296
// head-stage aliases (over WB0):
#define S_STATE 0
#define S_A1L   9216
#define S_REDS  17408
#define S_REDQ  18432

__device__ __forceinline__ int bt0f_off(int n, int k) {
  int g = n >> 7, w = (n >> 4) & 7, c = n & 15;
  int kk = k >> 5, q = (k >> 3) & 3, j = k & 7;
  return ((w * 3 + g) * 5 + kk) * 512 + (q * 16 + c) * 8 + j;
}

// Merged prologue, n-fastest mapping (coalesced reads everywhere).
// blocks 0..25: fold (Wp@Wx0 K=16 region + bias); blocks 26..729: pack.
__global__ void tlstm_prep(const float* __restrict__ Wp, const float* __restrict__ bp,
                           const float* __restrict__ Wx, const float* __restrict__ bx,
                           const float* __restrict__ Uh, const float* __restrict__ Wd,
                           __bf16* __restrict__ BT0f, __bf16* __restrict__ BWd0,
                           __bf16* __restrict__ BT1, __bf16* __restrict__ BWd1,
                           float* __restrict__ bz0) {
  if (blockIdx.x < 26) {
    int idx = blockIdx.x * 256 + threadIdx.x;          // (n fastest)
    if (idx >= 384 * 17) return;
    int kk = idx / 384, n = idx - kk * 384;
    int npr = n & 127, g = n >> 7, gs = g + 1;         // src gates 1,2,3 = i,o,c
    float sg = (g == 2) ? SCL_T : SCL_S;
    const float* wxg = Wx + (gs * 128) * 128 + npr;    // Wx[0][gs][h][npr]
    if (kk < 16) {
      const float* wprow = Wp + kk * 128;
      float s = 0.f;
      for (int h = 0; h < 128; ++h) s += wprow[h] * wxg[h * 128];   // lane-coalesced
      BT0f[bt0f_off(n, kk)] = (__bf16)(s * sg);
    } else {
      float s = bx[gs * 128 + npr];
      for (int h = 0; h < 128; ++h) s += bp[h] * wxg[h * 128];
      bz0[n] = s * sg;
      for (int k2 = 16; k2 < 32; ++k2) BT0f[bt0f_off(n, k2)] = (__bf16)0.f;  // K-pad
    }
    return;
  }
  int e = (blockIdx.x - 26) * 256 + threadIdx.x;
  if (e < 49152) {                                  // BT0f Uh0 (384n x 128k), n fastest
    int k = e / 384, n = e - k * 384;
    int npr = n & 127, g = n >> 7, gs = g + 1;
    float sg = (g == 2) ? SCL_T : SCL_S;
    BT0f[bt0f_off(n, k + 32)] = (__bf16)(Uh[(gs * 128 + k) * 128 + npr] * sg);
  } else if (e < 65536) {                           // BWd0 (128n x 128k), n fastest
    int e2 = e - 49152; int k = e2 >> 7, n = e2 & 127;
    BWd0[n * 128 + k] = (__bf16)(Wd[k * 128 + n] * SCL_T);
  } else if (e < 163840) {                          // BT1 (384n x 256k), n fastest
    int e2 = e - 65536; int k = e2 / 384, n = e2 - k * 384;
    int npr = n & 127, g = n >> 7, gs = g + 1;
    float sg = (g == 2) ? SCL_T : SCL_S;
    float v = (k < 128) ? Wx[((4 + gs) * 128 + k) * 128 + npr]
                        : Uh[((4 + gs) * 128 + (k - 128)) * 128 + npr];
    BT1[n * 256 + k] = (__bf16)(v * sg);
  } else if (e < 180224) {                          // BWd1 (128n x 128k), n fastest
    int e2 = e - 163840; int k = e2 >> 7, n = e2 & 127;
    BWd1[n * 128 + k] = (__bf16)(Wd[(128 + k) * 128 + n] * SCL_T);
  }
}

__global__ __launch_bounds__(512, 1) void tlstm_main(
    const float* __restrict__ hist, const float* __restrict__ hmask,
    const __bf16* __restrict__ BT0f, const __bf16* __restrict__ BWd0,
    const __bf16* __restrict__ BT1, const __bf16* __restrict__ BWd1,
    const float* __restrict__ bz0, const float* __restrict__ bx,
    const float* __restrict__ bd, const float* __restrict__ Wt,
    const float* __restrict__ bt, const float* __restrict__ lng,
    const float* __restrict__ lnb, const float* __restrict__ W1,
    const float* __restrict__ b1, const float* __restrict__ W2,
    const float* __restrict__ b2, float* __restrict__ out) {
  extern __shared__ __align__(16) char smem[];
  __bf16* WB0 = (__bf16*)(smem + S_WB0);
  __bf16 (*AH)[16][40]  = (__bf16(*)[16][40])(smem + S_AH);
  __bf16 (*A0H)[136]    = (__bf16(*)[136])(smem + S_A0H);
  __bf16 (*A1H)[136]    = (__bf16(*)[136])(smem + S_A1H);
  __bf16 (*AT0)[136]    = (__bf16(*)[136])(smem + S_AT0);
  __bf16 (*AT1)[136]    = (__bf16(*)[136])(smem + S_AT1);
  float (*dmL)[2][16]   = (float(*)[2][16])(smem + S_DM);   // [3 slots][d/m][row]
  int*   lastL          = (int*)(smem + S_LAST);
  float (*stateL)[144]  = (float(*)[144])(smem + S_STATE);
  float (*a1L)[128]     = (float(*)[128])(smem + S_A1L);
  float (*redS)[16]     = (float(*)[16])(smem + S_REDS);
  float (*redQ)[16]     = (float(*)[16])(smem + S_REDQ);

  const int tid  = threadIdx.x;
  const int wave = tid >> 6;
  const int lane = tid & 63;
  const int q    = lane >> 4;
  const int c16  = lane & 15;
  const int q8   = q * 8;
  const int b0   = blockIdx.x * 16;
  const int nc   = wave * 16 + c16;  // owned N-column (0..127)

  // ---- one-time init ----
  for (int i = tid * 8; i < 61440; i += 4096)          // BT0f -> LDS (linear copy)
    *(bf16x8*)(WB0 + i) = *(const bf16x8*)(BT0f + i);
  {
    __bf16* z = (__bf16*)(smem + S_AH);                // zero AH+A0H+A1H
    for (int i = tid; i < 5632; i += 512) z[i] = (__bf16)0.f;
  }
  if (tid < 16) {
    float s = 0.f;
    for (int t = 0; t < 64; ++t) s += hmask[(b0 + tid) * 64 + t];
    s = fminf(fmaxf(s, 1.f), 64.f);
    lastL[tid] = (int)s - 1;
  }

  // per-wave constants (biases prescaled)
  float bz0r[3], bz1r[3];
#pragma unroll
  for (int g = 0; g < 3; ++g) {
    float sg = (g == 2) ? SCL_T : SCL_S;
    bz0r[g] = bz0[g * 128 + nc];                 // already scaled in prep
    bz1r[g] = bx[(5 + g) * 128 + nc] * sg;
  }
  const float bd0r = bd[nc] * SCL_T,       bd1r = bd[128 + nc] * SCL_T;
  const float wt0r = Wt[nc] * SCL_S,       wt1r = Wt[128 + nc] * SCL_S;
  const float bt0r = bt[nc] * SCL_S,       bt1r = bt[128 + nc] * SCL_S;

  // frag-order WB0 bases: frag(g,kk) at ((wave*3+g)*5+kk)*512 + lane*8
  int offW[3];
#pragma unroll
  for (int g = 0; g < 3; ++g) offW[g] = ((wave * 3 + g) * 5) * 512 + lane * 8;

  // register weights: wf1 (24) + bwd0/1 (8) = 32 frags (proven no-spill)
  bf16x8 wf1[24], bwd0[4], bwd1[4];
#pragma unroll
  for (int g = 0; g < 3; ++g)
#pragma unroll
    for (int kk = 0; kk < 8; ++kk)
      wf1[g * 8 + kk] = *(const bf16x8*)(BT1 + (g * 128 + nc) * 256 + kk * 32 + q8);
#pragma unroll
  for (int kk = 0; kk < 4; ++kk) {
    bwd0[kk] = *(const bf16x8*)(BWd0 + nc * 128 + q8 + kk * 32);
    bwd1[kk] = *(const bf16x8*)(BWd1 + nc * 128 + q8 + kk * 32);
  }

  float h0r[4] = {}, c0r[4] = {}, h1r[4] = {}, c1r[4] = {}, encr[4] = {};

  __syncthreads();   // init complete

  int lrow[4];
#pragma unroll
  for (int r = 0; r < 4; ++r) lrow[r] = lastL[q * 4 + r];

  const int srow = (tid >> 4) & 15, scol = tid & 15;   // staging/head map (tid<256)
  const float* histrow = hist + (long)(b0 + srow) * 1024 + scol;
  const float* hmrow   = hmask + (long)(b0 + srow) * 64;

  // stage t=0 into dm slot 0 / AH slot 0; prefetch t=1
  float hv = 0.f, mv = 0.f;
  if (tid < 256) {
    float v0 = histrow[0];
    AH[0][srow][scol] = (__bf16)v0;
    if (scol == 5)
      dmL[0][0][srow] = __fdividef(1.f, __logf(2.7182818284590452f + fmaxf(v0, 0.f)));
    if (scol == 0) dmL[0][1][srow] = hmrow[0];
    hv = histrow[16];
    mv = hmrow[1];
  }
  __syncthreads();

  // lagged pipeline: iter t runs L0(t) and L1(t-1); t=64 drains L1(63).
  for (int t = 0; t <= 64; ++t) {
    const int p = t & 1, pn = p ^ 1;
    const int sp = t % 3, sm = (t + 2) % 3, sn = (t + 1) % 3;

    // ================= I1: gate GEMMs (independent chains, own loads) =========
    float otl0[4], otl1[4];
    if (t > 0) {    // L1 gates(t-1): z = [h0(t-1)|h1(t-2)] @ wf1 (K=256, regs)
      f32x4 acc[3];
#pragma unroll
      for (int g = 0; g < 3; ++g) acc[g] = (f32x4){bz1r[g], bz1r[g], bz1r[g], bz1r[g]};
#pragma unroll
      for (int kk = 0; kk < 4; ++kk) {
        bf16x8 a = *(const bf16x8*)&A0H[c16][kk * 32 + q8];
#pragma unroll
        for (int g = 0; g < 3; ++g) acc[g] = mfma16(a, wf1[g * 8 + kk], acc[g]);
      }
#pragma unroll
      for (int kk = 0; kk < 4; ++kk) {
        bf16x8 a = *(const bf16x8*)&A1H[c16][kk * 32 + q8];
#pragma unroll
        for (int g = 0; g < 3; ++g) acc[g] = mfma16(a, wf1[g * 8 + 4 + kk], acc[g]);
      }
#pragma unroll
      for (int r = 0; r < 4; ++r) {
        float ht = tanhE(acc[2][r]) + sigmE(acc[0][r]);
        otl1[r] = sigmE(acc[1][r]);
        AT1[q * 4 + r][nc] = (__bf16)ht;    // htl1 re-read from here in I2
      }
    }
    if (t < 64) {   // L0 gates(t): z = [hist|0|h0(t-1)] @ WB0f (K=160, LDS)
      f32x4 acc[3];
#pragma unroll
      for (int g = 0; g < 3; ++g) acc[g] = (f32x4){bz0r[g], bz0r[g], bz0r[g], bz0r[g]};
      {
        bf16x8 a = *(const bf16x8*)&AH[p][c16][q8];
#pragma unroll
        for (int g = 0; g < 3; ++g)
          acc[g] = mfma16(a, *(const bf16x8*)(WB0 + offW[g]), acc[g]);
      }
#pragma unroll
      for (int kk = 0; kk < 4; ++kk) {
        bf16x8 a = *(const bf16x8*)&A0H[c16][kk * 32 + q8];
#pragma unroll
        for (int g = 0; g < 3; ++g)
          acc[g] = mfma16(a, *(const bf16x8*)(WB0 + offW[g] + (kk + 1) * 512), acc[g]);
      }
#pragma unroll
      for (int r = 0; r < 4; ++r) {
        float ht = tanhE(acc[2][r]) + sigmE(acc[0][r]);
        otl0[r] = sigmE(acc[1][r]);
        AT0[q * 4 + r][nc] = (__bf16)ht;    // htl0 re-read from here in I2
      }
    }
    __syncthreads();   // B1

    // ================= I2: Wd GEMMs + state updates =================
    if (t < 64) {   // L0 update(t) -> h0(t) into A0H
      float drow[4], mrow[4];
#pragma unroll
      for (int r = 0; r < 4; ++r) {
        drow[r] = dmL[sp][0][q * 4 + r];
        mrow[r] = dmL[sp][1][q * 4 + r];
      }
      f32x4 accd = (f32x4){bd0r, bd0r, bd0r, bd0r};
#pragma unroll
      for (int kk = 0; kk < 4; ++kk) {
        bf16x8 a = *(const bf16x8*)&AT0[c16][kk * 32 + q8];
        accd = mfma16(a, bwd0[kk], accd);
      }
#pragma unroll
      for (int r = 0; r < 4; ++r) {
        float htl   = (float)AT0[q * 4 + r][nc];
        float hs    = tanhE(accd[r]);
        float dgate = sigmE(__fmaf_rn(drow[r], wt0r, bt0r));
        float hstar = __fmaf_rn(hs, dgate - 1.f, htl);
        float cn    = tanhE(SCL_T * __fmaf_rn(otl0[r], c0r[r], hstar));
        float hn    = otl0[r] * tanhE(SCL_T * cn);
        float m     = mrow[r];
        float hl    = __fmaf_rn(m, hn - h0r[r], h0r[r]);
        float cl    = __fmaf_rn(m, cn - c0r[r], c0r[r]);
        h0r[r] = hl; c0r[r] = cl;
        A0H[q * 4 + r][nc] = (__bf16)hl;
      }
    }
    if (t > 0) {    // L1 update(t-1) -> h1(t-1) into A1H; capture encoded
      float dpre[4], mpre[4];
#pragma unroll
      for (int r = 0; r < 4; ++r) {
        dpre[r] = dmL[sm][0][q * 4 + r];
        mpre[r] = dmL[sm][1][q * 4 + r];
      }
      f32x4 accd = (f32x4){bd1r, bd1r, bd1r, bd1r};
#pragma unroll
      for (int kk = 0; kk < 4; ++kk) {
        bf16x8 a = *(const bf16x8*)&AT1[c16][kk * 32 + q8];
        accd = mfma16(a, bwd1[kk], accd);
      }
      const int tm1 = t - 1;
#pragma unroll
      for (int r = 0; r < 4; ++r) {
        float htl   = (float)AT1[q * 4 + r][nc];
        float hs    = tanhE(accd[r]);
        float dgate = sigmE(__fmaf_rn(dpre[r], wt1r, bt1r));
        float hstar = __fmaf_rn(hs, dgate - 1.f, htl);
        float cn    = tanhE(SCL_T * __fmaf_rn(otl1[r], c1r[r], hstar));
        float hn    = otl1[r] * tanhE(SCL_T * cn);
        float m     = mpre[r];
        float hl    = __fmaf_rn(m, hn - h1r[r], h1r[r]);
        float cl    = __fmaf_rn(m, cn - c1r[r], c1r[r]);
        h1r[r] = hl; c1r[r] = cl;
        A1H[q * 4 + r][nc] = (__bf16)hl;
        if (tm1 == lrow[r]) encr[r] = hl * m;
      }
    }
    // stage t+1 into AH[pn] / dm slot sn (distinct from sp, sm)
    if (tid < 256 && t < 63) {
      AH[pn][srow][scol] = (__bf16)hv;
      if (scol == 5)
        dmL[sn][0][srow] = __fdividef(1.f, __logf(2.7182818284590452f + fmaxf(hv, 0.f)));
      if (scol == 0) dmL[sn][1][srow] = mv;
      if (t < 62) { hv = histrow[(t + 2) * 16]; mv = hmrow[t + 2]; }
    }
    __syncthreads();   // B2
  }

  // ---- decoder head: state = [hist[b,last,:16] | enc128]; LN; FC-ReLU-FC ----
  if (tid < 256)
    stateL[srow][scol] = hist[((long)(b0 + srow) * 64 + lastL[srow]) * 16 + scol];
#pragma unroll
  for (int r = 0; r < 4; ++r)
    stateL[q * 4 + r][16 + nc] = encr[r];
  __syncthreads();

  if (tid < 256) {
    float sm2 = 0.f, sq = 0.f;
    for (int k = scol; k < 144; k += 16) {
      float v = stateL[srow][k];
      sm2 += v; sq += v * v;
    }
    redS[srow][scol] = sm2; redQ[srow][scol] = sq;
  }
  __syncthreads();
  if (tid < 16) {
    float sm2 = 0.f, sq = 0.f;
    for (int s2 = 0; s2 < 16; ++s2) { sm2 += redS[tid][s2]; sq += redQ[tid][s2]; }
    float mu  = sm2 * (1.f / 144.f);
    float var = sq * (1.f / 144.f) - mu * mu;
    redS[0][tid] = mu;
    redQ[0][tid] = rsqrtf(var + 1e-5f);
  }
  __syncthreads();
  if (tid < 256) {
    float mu = redS[0][srow], rs = redQ[0][srow];
    for (int k = scol; k < 144; k += 16)
      stateL[srow][k] = (stateL[srow][k] - mu) * rs * lng[k] + lnb[k];
  }
  __syncthreads();
  if (tid < 256) {
    float accw[8];
#pragma unroll
    for (int o = 0; o < 8; ++o) accw[o] = b1[scol + 16 * o];
    for (int k = 0; k < 144; ++k) {
      float sv = stateL[srow][k];
      const float* w = W1 + k * 128 + scol;
#pragma unroll
      for (int o = 0; o < 8; ++o) accw[o] += sv * w[16 * o];
    }
#pragma unroll
    for (int o = 0; o < 8; ++o) a1L[srow][scol + 16 * o] = fmaxf(accw[o], 0.f);
  }
  __syncthreads();
  for (int e = tid; e < 960; e += 512) {
    int row = e / 60, j = e - row * 60;
    float accv = b2[j];
    for (int k = 0; k < 128; ++k) accv += a1L[row][k] * W2[k * 60 + j];
    accv = (accv != accv) ? 0.f : fminf(fmaxf(accv, -1e4f), 1e4f);  // nan_to_num
    out[(b0 + row) * 60 + j] = accv;
  }
}

extern "C" void kernel_launch(void* const* d_in, const int* in_sizes, int n_in,
                              void* d_out, int out_size, void* d_ws, size_t ws_size,
                              hipStream_t stream) {
  const float* hist  = (const float*)d_in[0];
  const float* hmask = (const float*)d_in[1];
  const float* Wp    = (const float*)d_in[2];
  const float* bp    = (const float*)d_in[3];
  const float* Wx    = (const float*)d_in[4];
  const float* bx    = (const float*)d_in[5];
  const float* Uh    = (const float*)d_in[6];
  const float* Wd    = (const float*)d_in[7];
  const float* bd    = (const float*)d_in[8];
  const float* Wt    = (const float*)d_in[9];
  const float* bt    = (const float*)d_in[10];
  const float* lng   = (const float*)d_in[11];
  const float* lnb   = (const float*)d_in[12];
  const float* W1    = (const float*)d_in[13];
  const float* b1    = (const float*)d_in[14];
  const float* W2    = (const float*)d_in[15];
  const float* b2    = (const float*)d_in[16];
  float* out = (float*)d_out;

  char* ws = (char*)d_ws;
  __bf16* BT0f = (__bf16*)ws;
  __bf16* BWd0 = (__bf16*)(ws + OFF_BWD0);
  __bf16* BT1  = (__bf16*)(ws + OFF_BT1);
  __bf16* BWd1 = (__bf16*)(ws + OFF_BWD1);
  float*  bz0  = (float*)(ws + OFF_BZ0);

  hipFuncSetAttribute((const void*)tlstm_main,
                      hipFuncAttributeMaxDynamicSharedMemorySize, S_TOTAL);

  tlstm_prep<<<730, 256, 0, stream>>>(Wp, bp, Wx, bx, Uh, Wd,
                                      BT0f, BWd0, BT1, BWd1, bz0);
  tlstm_main<<<256, 512, S_TOTAL, stream>>>(hist, hmask, BT0f, BWd0, BT1, BWd1,
                                            bz0, bx, bd, Wt, bt, lng, lnb,
                                            W1, b1, W2, b2, out);
}